// Round 1
// baseline (1758.031 us; speedup 1.0000x reference)
//
#include <hip/hip_runtime.h>
#include <hip/hip_bf16.h>
#include <math.h>

#define N_NODES 100000
#define N_EDGES 3200000
#define NUM_GRAPHS 2048
#define IN_CH 35
#define HID 128
#define BN_EPS 1e-5f

#define SCAN_CHUNK 512
#define NB_SCAN ((N_NODES + SCAN_CHUNK - 1) / SCAN_CHUNK)   // 196

__device__ __forceinline__ float gelu_f(float x) {
    return 0.5f * x * (1.0f + erff(x * 0.70710678118654752440f));
}

// ---------------- init / degree / dinv ----------------

__global__ void k_zero(int* __restrict__ deg, float* __restrict__ stats) {
    int i = blockIdx.x * blockDim.x + threadIdx.x;
    if (i < N_NODES) deg[i] = 0;
    if (i < 3 * 256) stats[i] = 0.0f;
}

__global__ void k_deg(const int* __restrict__ ei, int* __restrict__ deg) {
    int stride = gridDim.x * blockDim.x;
    for (int e = blockIdx.x * blockDim.x + threadIdx.x; e < N_EDGES; e += stride) {
        int d = ei[N_EDGES + e];   // dst row
        atomicAdd(&deg[d], 1);
    }
}

__global__ void k_dinv(const int* __restrict__ deg, float* __restrict__ dinv) {
    int i = blockIdx.x * blockDim.x + threadIdx.x;
    if (i < N_NODES) {
        float d = (float)(deg[i] + 1);   // +1 self loop
        dinv[i] = 1.0f / sqrtf(d);
    }
}

// ---------------- scan (CSR row_ptr) ----------------

__global__ void k_scan_partial(const int* __restrict__ deg, int* __restrict__ bsum) {
    __shared__ int red[256];
    int base = blockIdx.x * SCAN_CHUNK;
    int tid = threadIdx.x;
    int i0 = base + tid, i1 = base + 256 + tid;
    int v = 0;
    if (i0 < N_NODES) v += deg[i0];
    if (i1 < N_NODES) v += deg[i1];
    red[tid] = v;
    __syncthreads();
    for (int s = 128; s > 0; s >>= 1) {
        if (tid < s) red[tid] += red[tid + s];
        __syncthreads();
    }
    if (tid == 0) bsum[blockIdx.x] = red[0];
}

__global__ void k_scan_bsums(const int* __restrict__ bsum, int* __restrict__ boff,
                             int* __restrict__ rowp) {
    if (threadIdx.x == 0) {
        int run = 0;
        for (int i = 0; i < NB_SCAN; ++i) { boff[i] = run; run += bsum[i]; }
        rowp[N_NODES] = run;
    }
}

__global__ void k_scan_write(const int* __restrict__ deg, const int* __restrict__ boff,
                             int* __restrict__ rowp, int* __restrict__ cursor) {
    __shared__ int bufa[SCAN_CHUNK];
    __shared__ int bufb[SCAN_CHUNK];
    int base = blockIdx.x * SCAN_CHUNK;
    int tid = threadIdx.x;
    for (int i = tid; i < SCAN_CHUNK; i += 256) {
        int gi = base + i;
        bufa[i] = (gi < N_NODES) ? deg[gi] : 0;
    }
    __syncthreads();
    int* src = bufa;
    int* dst = bufb;
    for (int st = 1; st < SCAN_CHUNK; st <<= 1) {
        for (int i = tid; i < SCAN_CHUNK; i += 256) {
            int v = src[i];
            if (i >= st) v += src[i - st];
            dst[i] = v;
        }
        __syncthreads();
        int* t = src; src = dst; dst = t;
    }
    int off = boff[blockIdx.x];
    for (int i = tid; i < SCAN_CHUNK; i += 256) {
        int gi = base + i;
        if (gi < N_NODES) {
            int ex = (i == 0) ? 0 : src[i - 1];
            int val = off + ex;
            rowp[gi] = val;
            cursor[gi] = val;
        }
    }
}

__global__ void k_place(const int* __restrict__ ei, int* __restrict__ cursor,
                        int* __restrict__ col) {
    int stride = gridDim.x * blockDim.x;
    for (int e = blockIdx.x * blockDim.x + threadIdx.x; e < N_EDGES; e += stride) {
        int s = ei[e];
        int d = ei[N_EDGES + e];
        int p = atomicAdd(&cursor[d], 1);
        col[p] = s;
    }
}

// ---------------- GEMM: H = act(X) @ W ----------------
// X: [N, K], W: [K, 128], out: [N, 128]. 32 rows per block, 256 threads.

template <int K, bool ACT>
__global__ void k_gemm(const float* __restrict__ X, const float* __restrict__ W,
                       const float* __restrict__ sc, const float* __restrict__ sh,
                       float* __restrict__ H) {
    __shared__ float xs[32 * K];
    int tid = threadIdx.x;
    int row0 = blockIdx.x * 32;
    for (int idx = tid; idx < 32 * K; idx += 256) {
        int r = idx / K;
        int k = idx - r * K;
        int gr = row0 + r;
        float v = 0.0f;
        if (gr < N_NODES) {
            v = X[(size_t)gr * K + k];
            if (ACT) v = gelu_f(v * sc[k] + sh[k]);
        }
        xs[idx] = v;
    }
    __syncthreads();
    int tx = tid & 31;   // col group: cols tx*4 .. tx*4+3
    int ty = tid >> 5;   // row group: rows ty*4 .. ty*4+3
    float acc[4][4] = {};
    for (int k = 0; k < K; ++k) {
        float4 w = *(const float4*)&W[k * HID + tx * 4];
        #pragma unroll
        for (int rr = 0; rr < 4; ++rr) {
            float x = xs[(ty * 4 + rr) * K + k];
            acc[rr][0] = fmaf(x, w.x, acc[rr][0]);
            acc[rr][1] = fmaf(x, w.y, acc[rr][1]);
            acc[rr][2] = fmaf(x, w.z, acc[rr][2]);
            acc[rr][3] = fmaf(x, w.w, acc[rr][3]);
        }
    }
    #pragma unroll
    for (int rr = 0; rr < 4; ++rr) {
        int gr = row0 + ty * 4 + rr;
        if (gr < N_NODES) {
            float4 o = make_float4(acc[rr][0], acc[rr][1], acc[rr][2], acc[rr][3]);
            *(float4*)&H[(size_t)gr * HID + tx * 4] = o;
        }
    }
}

// ---------------- gather conv: Y = dinv_i*(sum_e dinv_s*H_s + dinv_i*H_i) + b ----------------
// 2 nodes per 256-thread block; thread = channel.

__global__ void k_conv(const float* __restrict__ H, const int* __restrict__ rowp,
                       const int* __restrict__ col, const float* __restrict__ dinv,
                       const float* __restrict__ bias, float* __restrict__ Y) {
    int node = blockIdx.x * 2 + (threadIdx.x >> 7);
    int c = threadIdx.x & 127;
    if (node >= N_NODES) return;
    int rp0 = rowp[node];
    int rp1 = rowp[node + 1];
    float di = dinv[node];
    float acc = di * H[(size_t)node * HID + c];
    int e = rp0;
    for (; e + 4 <= rp1; e += 4) {
        int s0 = col[e], s1 = col[e + 1], s2 = col[e + 2], s3 = col[e + 3];
        float a0 = dinv[s0], a1 = dinv[s1], a2 = dinv[s2], a3 = dinv[s3];
        float h0 = H[(size_t)s0 * HID + c];
        float h1 = H[(size_t)s1 * HID + c];
        float h2 = H[(size_t)s2 * HID + c];
        float h3 = H[(size_t)s3 * HID + c];
        acc = fmaf(a0, h0, acc);
        acc = fmaf(a1, h1, acc);
        acc = fmaf(a2, h2, acc);
        acc = fmaf(a3, h3, acc);
    }
    for (; e < rp1; ++e) {
        int s = col[e];
        acc = fmaf(dinv[s], H[(size_t)s * HID + c], acc);
    }
    Y[(size_t)node * HID + c] = di * acc + bias[c];
}

// ---------------- BN stats: per-channel sum & sumsq ----------------

__global__ void k_stats(const float* __restrict__ Y, float* __restrict__ stats) {
    __shared__ float ls[256];
    __shared__ float lss[256];
    int tid = threadIdx.x;
    int c = tid & 127;
    int half = tid >> 7;
    float s = 0.0f, ss = 0.0f;
    for (int r = blockIdx.x * 2 + half; r < N_NODES; r += gridDim.x * 2) {
        float v = Y[(size_t)r * HID + c];
        s += v;
        ss = fmaf(v, v, ss);
    }
    ls[tid] = s;
    lss[tid] = ss;
    __syncthreads();
    if (tid < 128) {
        float st = ls[tid] + ls[tid + 128];
        float sst = lss[tid] + lss[tid + 128];
        atomicAdd(&stats[c], st);
        atomicAdd(&stats[128 + c], sst);
    }
}

__global__ void k_bnfinal(const float* __restrict__ stats, const float* __restrict__ g,
                          const float* __restrict__ be, float* __restrict__ sc,
                          float* __restrict__ sh) {
    int c = threadIdx.x;
    if (c < 128) {
        const float inv_n = 1.0f / (float)N_NODES;
        float mean = stats[c] * inv_n;
        float var = stats[128 + c] * inv_n - mean * mean;
        float s = g[c] * rsqrtf(var + BN_EPS);
        sc[c] = s;
        sh[c] = be[c] - mean * s;
    }
}

// ---------------- fused pool + MLP head ----------------

__device__ __forceinline__ int lowerb(const int* __restrict__ arr, int n, int key) {
    int lo = 0, hi = n;
    while (lo < hi) {
        int mid = (lo + hi) >> 1;
        if (arr[mid] < key) lo = mid + 1; else hi = mid;
    }
    return lo;
}

__global__ void k_pool_mlp(const float* __restrict__ Y, const float* __restrict__ sc,
                           const float* __restrict__ sh, const int* __restrict__ batch,
                           const float* __restrict__ Wl1, const float* __restrict__ bl1,
                           const float* __restrict__ Wl2, const float* __restrict__ bl2,
                           float* __restrict__ out) {
    __shared__ float pooled[128];
    __shared__ int bounds[2];
    int g = blockIdx.x;
    int tid = threadIdx.x;
    if (tid == 0) {
        bounds[0] = lowerb(batch, N_NODES, g);
        bounds[1] = lowerb(batch, N_NODES, g + 1);
    }
    __syncthreads();
    int lo = bounds[0], hi = bounds[1];
    float s = sc[tid], h = sh[tid];
    float acc = 0.0f;
    for (int r = lo; r < hi; ++r)
        acc += gelu_f(Y[(size_t)r * HID + tid] * s + h);
    pooled[tid] = (hi > lo) ? acc / (float)(hi - lo) : 0.0f;
    __syncthreads();
    if (tid < 64) {
        float hs = bl1[tid];
        #pragma unroll 4
        for (int k = 0; k < 128; ++k)
            hs = fmaf(pooled[k], Wl1[k * 64 + tid], hs);
        float e = (hs > 0.0f) ? hs : expm1f(hs);
        float part = e * Wl2[tid];
        #pragma unroll
        for (int o = 32; o > 0; o >>= 1)
            part += __shfl_down(part, o);
        if (tid == 0) out[g] = part + bl2[0];
    }
}

// ---------------- host launch ----------------

extern "C" void kernel_launch(void* const* d_in, const int* in_sizes, int n_in,
                              void* d_out, int out_size, void* d_ws, size_t ws_size,
                              hipStream_t stream) {
    const float* x   = (const float*)d_in[0];
    const int*   ei  = (const int*)d_in[1];
    const int*   bat = (const int*)d_in[2];
    const float* W1  = (const float*)d_in[3];
    const float* b1  = (const float*)d_in[4];
    const float* g1  = (const float*)d_in[5];
    const float* be1 = (const float*)d_in[6];
    const float* W2  = (const float*)d_in[7];
    const float* b2  = (const float*)d_in[8];
    const float* g2  = (const float*)d_in[9];
    const float* be2 = (const float*)d_in[10];
    const float* W3  = (const float*)d_in[11];
    const float* b3  = (const float*)d_in[12];
    const float* g3  = (const float*)d_in[13];
    const float* be3 = (const float*)d_in[14];
    const float* Wl1 = (const float*)d_in[15];
    const float* bl1 = (const float*)d_in[16];
    const float* Wl2 = (const float*)d_in[17];
    const float* bl2 = (const float*)d_in[18];
    float* out = (float*)d_out;

    char* ws = (char*)d_ws;
    size_t off = 0;
    auto alloc = [&](size_t bytes) -> char* {
        char* p = ws + off;
        off += (bytes + 255) & ~(size_t)255;
        return p;
    };
    int*   deg    = (int*)alloc(N_NODES * sizeof(int));
    float* dinv   = (float*)alloc(N_NODES * sizeof(float));
    int*   rowp   = (int*)alloc((N_NODES + 1) * sizeof(int));
    int*   cursor = (int*)alloc(N_NODES * sizeof(int));
    int*   bsum   = (int*)alloc(NB_SCAN * sizeof(int));
    int*   boff   = (int*)alloc(NB_SCAN * sizeof(int));
    int*   col    = (int*)alloc((size_t)N_EDGES * sizeof(int));
    float* A      = (float*)alloc((size_t)N_NODES * HID * sizeof(float));
    float* B      = (float*)alloc((size_t)N_NODES * HID * sizeof(float));
    float* stats  = (float*)alloc(3 * 256 * sizeof(float));  // [layer][sum(128),sumsq(128)]
    float* ss     = (float*)alloc(3 * 256 * sizeof(float));  // [layer][scale(128),shift(128)]

    // ---- graph structure ----
    k_zero<<<(N_NODES + 255) / 256, 256, 0, stream>>>(deg, stats);
    k_deg<<<2048, 256, 0, stream>>>(ei, deg);
    k_dinv<<<(N_NODES + 255) / 256, 256, 0, stream>>>(deg, dinv);
    k_scan_partial<<<NB_SCAN, 256, 0, stream>>>(deg, bsum);
    k_scan_bsums<<<1, 64, 0, stream>>>(bsum, boff, rowp);
    k_scan_write<<<NB_SCAN, 256, 0, stream>>>(deg, boff, rowp, cursor);
    k_place<<<2048, 256, 0, stream>>>(ei, cursor, col);

    const int gemm_blocks = (N_NODES + 31) / 32;
    const int conv_blocks = (N_NODES + 1) / 2;

    // ---- layer 1 ----
    k_gemm<IN_CH, false><<<gemm_blocks, 256, 0, stream>>>(x, W1, nullptr, nullptr, A);
    k_conv<<<conv_blocks, 256, 0, stream>>>(A, rowp, col, dinv, b1, B);
    k_stats<<<1024, 256, 0, stream>>>(B, stats + 0 * 256);
    k_bnfinal<<<1, 128, 0, stream>>>(stats + 0 * 256, g1, be1, ss + 0 * 256, ss + 0 * 256 + 128);

    // ---- layer 2 ----
    k_gemm<HID, true><<<gemm_blocks, 256, 0, stream>>>(B, W2, ss + 0 * 256, ss + 0 * 256 + 128, A);
    k_conv<<<conv_blocks, 256, 0, stream>>>(A, rowp, col, dinv, b2, B);
    k_stats<<<1024, 256, 0, stream>>>(B, stats + 1 * 256);
    k_bnfinal<<<1, 128, 0, stream>>>(stats + 1 * 256, g2, be2, ss + 1 * 256, ss + 1 * 256 + 128);

    // ---- layer 3 ----
    k_gemm<HID, true><<<gemm_blocks, 256, 0, stream>>>(B, W3, ss + 1 * 256, ss + 1 * 256 + 128, A);
    k_conv<<<conv_blocks, 256, 0, stream>>>(A, rowp, col, dinv, b3, B);
    k_stats<<<1024, 256, 0, stream>>>(B, stats + 2 * 256);
    k_bnfinal<<<1, 128, 0, stream>>>(stats + 2 * 256, g3, be3, ss + 2 * 256, ss + 2 * 256 + 128);

    // ---- pool + head ----
    k_pool_mlp<<<NUM_GRAPHS, 128, 0, stream>>>(B, ss + 2 * 256, ss + 2 * 256 + 128, bat,
                                               Wl1, bl1, Wl2, bl2, out);
}

// Round 2
// 1506.809 us; speedup vs baseline: 1.1667x; 1.1667x over previous
//
#include <hip/hip_runtime.h>
#include <hip/hip_bf16.h>
#include <math.h>

#define N_NODES 100000
#define N_EDGES 3200000
#define NUM_GRAPHS 2048
#define IN_CH 35
#define HID 128
#define BN_EPS 1e-5f

#define BUCK_SHIFT 9
#define BUCK_SIZE (1 << BUCK_SHIFT)                       // 512 nodes per bucket
#define NB_BUCK ((N_NODES + BUCK_SIZE - 1) / BUCK_SIZE)   // 196
#define BIN_GRID 1024
#define BIN_CHUNK ((N_EDGES + BIN_GRID - 1) / BIN_GRID)   // 3125

__device__ __forceinline__ float gelu_f(float x) {
    return 0.5f * x * (1.0f + erff(x * 0.70710678118654752440f));
}

// ---------------- zero bucket counters + stats ----------------

__global__ void k_zero2(int* __restrict__ bcnt, float* __restrict__ stats) {
    int i = threadIdx.x;
    if (i < NB_BUCK) bcnt[i] = 0;
    if (i < 3 * 256) stats[i] = 0.0f;
}

// ---------------- bucket histogram (LDS-aggregated) ----------------

__global__ void k_bhist(const int* __restrict__ ei, int* __restrict__ bcnt) {
    __shared__ int hist[NB_BUCK];
    int tid = threadIdx.x;
    if (tid < NB_BUCK) hist[tid] = 0;
    __syncthreads();
    int e0 = blockIdx.x * BIN_CHUNK;
    int e1 = min(e0 + BIN_CHUNK, N_EDGES);
    for (int e = e0 + tid; e < e1; e += 256) {
        int d = ei[N_EDGES + e];
        atomicAdd(&hist[d >> BUCK_SHIFT], 1);
    }
    __syncthreads();
    if (tid < NB_BUCK && hist[tid] > 0) atomicAdd(&bcnt[tid], hist[tid]);
}

// ---------------- bucket scan: bbase (exclusive), init bcursor ----------------

__global__ void k_bscan(const int* __restrict__ bcnt, int* __restrict__ bbase,
                        int* __restrict__ bcursor, int* __restrict__ rowp) {
    __shared__ int sa[256];
    __shared__ int sb[256];
    int tid = threadIdx.x;
    sa[tid] = (tid < NB_BUCK) ? bcnt[tid] : 0;
    __syncthreads();
    int* src = sa; int* dst = sb;
    for (int st = 1; st < 256; st <<= 1) {
        int v = src[tid];
        if (tid >= st) v += src[tid - st];
        dst[tid] = v;
        __syncthreads();
        int* t = src; src = dst; dst = t;
    }
    // src holds inclusive scan
    if (tid < NB_BUCK) {
        int ex = (tid == 0) ? 0 : src[tid - 1];
        bbase[tid] = ex;
        bcursor[tid] = ex;
    }
    if (tid == 0) {
        bbase[NB_BUCK] = N_EDGES;
        rowp[N_NODES] = N_EDGES;
    }
}

// ---------------- bin: block-aggregated scatter into bucket-contiguous SoA ----------------

__global__ void k_bin(const int* __restrict__ ei, int* __restrict__ bcursor,
                      int* __restrict__ bsrc, int* __restrict__ bdst) {
    __shared__ int hist[NB_BUCK];
    __shared__ int hbase[NB_BUCK];
    __shared__ int lcur[NB_BUCK];
    int tid = threadIdx.x;
    if (tid < NB_BUCK) { hist[tid] = 0; lcur[tid] = 0; }
    __syncthreads();
    int e0 = blockIdx.x * BIN_CHUNK;
    int e1 = min(e0 + BIN_CHUNK, N_EDGES);
    for (int e = e0 + tid; e < e1; e += 256) {
        int d = ei[N_EDGES + e];
        atomicAdd(&hist[d >> BUCK_SHIFT], 1);
    }
    __syncthreads();
    if (tid < NB_BUCK) {
        int h = hist[tid];
        hbase[tid] = (h > 0) ? atomicAdd(&bcursor[tid], h) : 0;
    }
    __syncthreads();
    for (int e = e0 + tid; e < e1; e += 256) {
        int s = ei[e];
        int d = ei[N_EDGES + e];
        int b = d >> BUCK_SHIFT;
        int off = atomicAdd(&lcur[b], 1);
        int idx = hbase[b] + off;
        bsrc[idx] = s;
        bdst[idx] = d;
    }
}

// ---------------- fill: per-bucket degree, rowp, dinv, CSR placement ----------------
// one block (512 threads) per bucket; all cursors in LDS, col writes confined to
// a ~64KB window -> L2-resident, no write amplification, zero global atomics.

__global__ void k_fill(const int* __restrict__ bbase, const int* __restrict__ bsrc,
                       const int* __restrict__ bdst, int* __restrict__ rowp,
                       float* __restrict__ dinv, int* __restrict__ col) {
    __shared__ int ldeg[BUCK_SIZE];
    __shared__ int sa[BUCK_SIZE];
    __shared__ int sb[BUCK_SIZE];
    __shared__ int lcur[BUCK_SIZE];
    int b = blockIdx.x;
    int tid = threadIdx.x;
    int base_node = b << BUCK_SHIFT;
    int nn = min(BUCK_SIZE, N_NODES - base_node);
    int seg0 = bbase[b];
    int seg1 = bbase[b + 1];
    ldeg[tid] = 0;
    __syncthreads();
    for (int e = seg0 + tid; e < seg1; e += BUCK_SIZE) {
        int d = bdst[e];
        atomicAdd(&ldeg[d - base_node], 1);
    }
    __syncthreads();
    sa[tid] = ldeg[tid];
    __syncthreads();
    int* src = sa; int* dst = sb;
    for (int st = 1; st < BUCK_SIZE; st <<= 1) {
        int v = src[tid];
        if (tid >= st) v += src[tid - st];
        dst[tid] = v;
        __syncthreads();
        int* t = src; src = dst; dst = t;
    }
    // src = inclusive scan of ldeg
    int ex = (tid == 0) ? 0 : src[tid - 1];
    int rp = seg0 + ex;
    lcur[tid] = rp;
    if (tid < nn) {
        rowp[base_node + tid] = rp;
        dinv[base_node + tid] = rsqrtf((float)(ldeg[tid] + 1));
    }
    __syncthreads();
    for (int e = seg0 + tid; e < seg1; e += BUCK_SIZE) {
        int s = bsrc[e];
        int d = bdst[e];
        int p = atomicAdd(&lcur[d - base_node], 1);
        col[p] = s;
    }
}

// ---------------- GEMM: H = act(X) @ W ----------------

template <int K, bool ACT>
__global__ void k_gemm(const float* __restrict__ X, const float* __restrict__ W,
                       const float* __restrict__ sc, const float* __restrict__ sh,
                       float* __restrict__ H) {
    __shared__ float xs[32 * K];
    int tid = threadIdx.x;
    int row0 = blockIdx.x * 32;
    for (int idx = tid; idx < 32 * K; idx += 256) {
        int r = idx / K;
        int k = idx - r * K;
        int gr = row0 + r;
        float v = 0.0f;
        if (gr < N_NODES) {
            v = X[(size_t)gr * K + k];
            if (ACT) v = gelu_f(v * sc[k] + sh[k]);
        }
        xs[idx] = v;
    }
    __syncthreads();
    int tx = tid & 31;
    int ty = tid >> 5;
    float acc[4][4] = {};
    for (int k = 0; k < K; ++k) {
        float4 w = *(const float4*)&W[k * HID + tx * 4];
        #pragma unroll
        for (int rr = 0; rr < 4; ++rr) {
            float x = xs[(ty * 4 + rr) * K + k];
            acc[rr][0] = fmaf(x, w.x, acc[rr][0]);
            acc[rr][1] = fmaf(x, w.y, acc[rr][1]);
            acc[rr][2] = fmaf(x, w.z, acc[rr][2]);
            acc[rr][3] = fmaf(x, w.w, acc[rr][3]);
        }
    }
    #pragma unroll
    for (int rr = 0; rr < 4; ++rr) {
        int gr = row0 + ty * 4 + rr;
        if (gr < N_NODES) {
            float4 o = make_float4(acc[rr][0], acc[rr][1], acc[rr][2], acc[rr][3]);
            *(float4*)&H[(size_t)gr * HID + tx * 4] = o;
        }
    }
}

// ---------------- gather conv ----------------

__global__ void k_conv(const float* __restrict__ H, const int* __restrict__ rowp,
                       const int* __restrict__ col, const float* __restrict__ dinv,
                       const float* __restrict__ bias, float* __restrict__ Y) {
    int node = blockIdx.x * 2 + (threadIdx.x >> 7);
    int c = threadIdx.x & 127;
    if (node >= N_NODES) return;
    int rp0 = rowp[node];
    int rp1 = rowp[node + 1];
    float di = dinv[node];
    float acc = di * H[(size_t)node * HID + c];
    int e = rp0;
    for (; e + 4 <= rp1; e += 4) {
        int s0 = col[e], s1 = col[e + 1], s2 = col[e + 2], s3 = col[e + 3];
        float a0 = dinv[s0], a1 = dinv[s1], a2 = dinv[s2], a3 = dinv[s3];
        float h0 = H[(size_t)s0 * HID + c];
        float h1 = H[(size_t)s1 * HID + c];
        float h2 = H[(size_t)s2 * HID + c];
        float h3 = H[(size_t)s3 * HID + c];
        acc = fmaf(a0, h0, acc);
        acc = fmaf(a1, h1, acc);
        acc = fmaf(a2, h2, acc);
        acc = fmaf(a3, h3, acc);
    }
    for (; e < rp1; ++e) {
        int s = col[e];
        acc = fmaf(dinv[s], H[(size_t)s * HID + c], acc);
    }
    Y[(size_t)node * HID + c] = di * acc + bias[c];
}

// ---------------- BN stats ----------------

__global__ void k_stats(const float* __restrict__ Y, float* __restrict__ stats) {
    __shared__ float ls[256];
    __shared__ float lss[256];
    int tid = threadIdx.x;
    int c = tid & 127;
    int half = tid >> 7;
    float s = 0.0f, ss = 0.0f;
    for (int r = blockIdx.x * 2 + half; r < N_NODES; r += gridDim.x * 2) {
        float v = Y[(size_t)r * HID + c];
        s += v;
        ss = fmaf(v, v, ss);
    }
    ls[tid] = s;
    lss[tid] = ss;
    __syncthreads();
    if (tid < 128) {
        float st = ls[tid] + ls[tid + 128];
        float sst = lss[tid] + lss[tid + 128];
        atomicAdd(&stats[c], st);
        atomicAdd(&stats[128 + c], sst);
    }
}

__global__ void k_bnfinal(const float* __restrict__ stats, const float* __restrict__ g,
                          const float* __restrict__ be, float* __restrict__ sc,
                          float* __restrict__ sh) {
    int c = threadIdx.x;
    if (c < 128) {
        const float inv_n = 1.0f / (float)N_NODES;
        float mean = stats[c] * inv_n;
        float var = stats[128 + c] * inv_n - mean * mean;
        float s = g[c] * rsqrtf(var + BN_EPS);
        sc[c] = s;
        sh[c] = be[c] - mean * s;
    }
}

// ---------------- fused pool + MLP head ----------------

__device__ __forceinline__ int lowerb(const int* __restrict__ arr, int n, int key) {
    int lo = 0, hi = n;
    while (lo < hi) {
        int mid = (lo + hi) >> 1;
        if (arr[mid] < key) lo = mid + 1; else hi = mid;
    }
    return lo;
}

__global__ void k_pool_mlp(const float* __restrict__ Y, const float* __restrict__ sc,
                           const float* __restrict__ sh, const int* __restrict__ batch,
                           const float* __restrict__ Wl1, const float* __restrict__ bl1,
                           const float* __restrict__ Wl2, const float* __restrict__ bl2,
                           float* __restrict__ out) {
    __shared__ float pooled[128];
    __shared__ int bounds[2];
    int g = blockIdx.x;
    int tid = threadIdx.x;
    if (tid == 0) {
        bounds[0] = lowerb(batch, N_NODES, g);
        bounds[1] = lowerb(batch, N_NODES, g + 1);
    }
    __syncthreads();
    int lo = bounds[0], hi = bounds[1];
    float s = sc[tid], h = sh[tid];
    float acc = 0.0f;
    for (int r = lo; r < hi; ++r)
        acc += gelu_f(Y[(size_t)r * HID + tid] * s + h);
    pooled[tid] = (hi > lo) ? acc / (float)(hi - lo) : 0.0f;
    __syncthreads();
    if (tid < 64) {
        float hs = bl1[tid];
        #pragma unroll 4
        for (int k = 0; k < 128; ++k)
            hs = fmaf(pooled[k], Wl1[k * 64 + tid], hs);
        float e = (hs > 0.0f) ? hs : expm1f(hs);
        float part = e * Wl2[tid];
        #pragma unroll
        for (int o = 32; o > 0; o >>= 1)
            part += __shfl_down(part, o);
        if (tid == 0) out[g] = part + bl2[0];
    }
}

// ---------------- host launch ----------------

extern "C" void kernel_launch(void* const* d_in, const int* in_sizes, int n_in,
                              void* d_out, int out_size, void* d_ws, size_t ws_size,
                              hipStream_t stream) {
    const float* x   = (const float*)d_in[0];
    const int*   ei  = (const int*)d_in[1];
    const int*   bat = (const int*)d_in[2];
    const float* W1  = (const float*)d_in[3];
    const float* b1  = (const float*)d_in[4];
    const float* g1  = (const float*)d_in[5];
    const float* be1 = (const float*)d_in[6];
    const float* W2  = (const float*)d_in[7];
    const float* b2  = (const float*)d_in[8];
    const float* g2  = (const float*)d_in[9];
    const float* be2 = (const float*)d_in[10];
    const float* W3  = (const float*)d_in[11];
    const float* b3  = (const float*)d_in[12];
    const float* g3  = (const float*)d_in[13];
    const float* be3 = (const float*)d_in[14];
    const float* Wl1 = (const float*)d_in[15];
    const float* bl1 = (const float*)d_in[16];
    const float* Wl2 = (const float*)d_in[17];
    const float* bl2 = (const float*)d_in[18];
    float* out = (float*)d_out;

    char* ws = (char*)d_ws;
    size_t off = 0;
    auto alloc = [&](size_t bytes) -> char* {
        char* p = ws + off;
        off += (bytes + 255) & ~(size_t)255;
        return p;
    };
    int*   bcnt    = (int*)alloc(NB_BUCK * sizeof(int));
    int*   bbase   = (int*)alloc((NB_BUCK + 1) * sizeof(int));
    int*   bcursor = (int*)alloc(NB_BUCK * sizeof(int));
    int*   bsrc    = (int*)alloc((size_t)N_EDGES * sizeof(int));
    int*   bdst    = (int*)alloc((size_t)N_EDGES * sizeof(int));
    int*   rowp    = (int*)alloc((N_NODES + 1) * sizeof(int));
    float* dinv    = (float*)alloc(N_NODES * sizeof(float));
    int*   col     = (int*)alloc((size_t)N_EDGES * sizeof(int));
    float* A       = (float*)alloc((size_t)N_NODES * HID * sizeof(float));
    float* B       = (float*)alloc((size_t)N_NODES * HID * sizeof(float));
    float* stats   = (float*)alloc(3 * 256 * sizeof(float));
    float* ss      = (float*)alloc(3 * 256 * sizeof(float));

    // ---- graph structure ----
    k_zero2<<<1, 1024, 0, stream>>>(bcnt, stats);
    k_bhist<<<BIN_GRID, 256, 0, stream>>>(ei, bcnt);
    k_bscan<<<1, 256, 0, stream>>>(bcnt, bbase, bcursor, rowp);
    k_bin<<<BIN_GRID, 256, 0, stream>>>(ei, bcursor, bsrc, bdst);
    k_fill<<<NB_BUCK, BUCK_SIZE, 0, stream>>>(bbase, bsrc, bdst, rowp, dinv, col);

    const int gemm_blocks = (N_NODES + 31) / 32;
    const int conv_blocks = (N_NODES + 1) / 2;

    // ---- layer 1 ----
    k_gemm<IN_CH, false><<<gemm_blocks, 256, 0, stream>>>(x, W1, nullptr, nullptr, A);
    k_conv<<<conv_blocks, 256, 0, stream>>>(A, rowp, col, dinv, b1, B);
    k_stats<<<1024, 256, 0, stream>>>(B, stats + 0 * 256);
    k_bnfinal<<<1, 128, 0, stream>>>(stats + 0 * 256, g1, be1, ss + 0 * 256, ss + 0 * 256 + 128);

    // ---- layer 2 ----
    k_gemm<HID, true><<<gemm_blocks, 256, 0, stream>>>(B, W2, ss + 0 * 256, ss + 0 * 256 + 128, A);
    k_conv<<<conv_blocks, 256, 0, stream>>>(A, rowp, col, dinv, b2, B);
    k_stats<<<1024, 256, 0, stream>>>(B, stats + 1 * 256);
    k_bnfinal<<<1, 128, 0, stream>>>(stats + 1 * 256, g2, be2, ss + 1 * 256, ss + 1 * 256 + 128);

    // ---- layer 3 ----
    k_gemm<HID, true><<<gemm_blocks, 256, 0, stream>>>(B, W3, ss + 1 * 256, ss + 1 * 256 + 128, A);
    k_conv<<<conv_blocks, 256, 0, stream>>>(A, rowp, col, dinv, b3, B);
    k_stats<<<1024, 256, 0, stream>>>(B, stats + 2 * 256);
    k_bnfinal<<<1, 128, 0, stream>>>(stats + 2 * 256, g3, be3, ss + 2 * 256, ss + 2 * 256 + 128);

    // ---- pool + head ----
    k_pool_mlp<<<NUM_GRAPHS, 128, 0, stream>>>(B, ss + 2 * 256, ss + 2 * 256 + 128, bat,
                                               Wl1, bl1, Wl2, bl2, out);
}

// Round 3
// 1258.480 us; speedup vs baseline: 1.3969x; 1.1973x over previous
//
#include <hip/hip_runtime.h>
#include <hip/hip_bf16.h>
#include <math.h>

#define N_NODES 100000
#define N_EDGES 3200000
#define NUM_GRAPHS 2048
#define IN_CH 35
#define HID 128
#define BN_EPS 1e-5f

#define BUCK_SHIFT 9
#define BUCK_SIZE 512
#define NB_BUCK 196          // ceil(100000/512)
#define BIN_GRID 1024
#define BIN_CHUNK 3125       // ceil(3200000/1024)

__device__ __forceinline__ float gelu_f(float x) {
    return 0.5f * x * (1.0f + erff(x * 0.70710678118654752440f));
}

// bf16 helpers: packed 2 x bf16 in a uint (lo = even channel, hi = odd channel)
__device__ __forceinline__ float bflo(unsigned v) { return __uint_as_float(v << 16); }
__device__ __forceinline__ float bfhi(unsigned v) { return __uint_as_float(v & 0xffff0000u); }
__device__ __forceinline__ unsigned f2bf(float f) {
    unsigned x = __float_as_uint(f);
    return (x + 0x7fffu + ((x >> 16) & 1u)) >> 16;   // RNE
}
__device__ __forceinline__ unsigned packbf2(float lo, float hi) {
    return f2bf(lo) | (f2bf(hi) << 16);
}

// ---------------- zero bucket counters + stats ----------------

__global__ void k_zero2(int* __restrict__ bcnt, float* __restrict__ stats) {
    int i = threadIdx.x;
    if (i < NB_BUCK) bcnt[i] = 0;
    if (i < 3 * 256) stats[i] = 0.0f;
}

// ---------------- bucket histogram (LDS-aggregated) ----------------

__global__ void k_bhist(const int* __restrict__ ei, int* __restrict__ bcnt) {
    __shared__ int hist[NB_BUCK];
    int tid = threadIdx.x;
    if (tid < NB_BUCK) hist[tid] = 0;
    __syncthreads();
    int e0 = blockIdx.x * BIN_CHUNK;
    int e1 = min(e0 + BIN_CHUNK, N_EDGES);
    for (int e = e0 + tid; e < e1; e += 256) {
        int d = ei[N_EDGES + e];
        atomicAdd(&hist[d >> BUCK_SHIFT], 1);
    }
    __syncthreads();
    if (tid < NB_BUCK && hist[tid] > 0) atomicAdd(&bcnt[tid], hist[tid]);
}

// ---------------- bucket scan ----------------

__global__ void k_bscan(const int* __restrict__ bcnt, int* __restrict__ bbase,
                        int* __restrict__ bcursor, int* __restrict__ rowp) {
    __shared__ int sa[256];
    __shared__ int sb[256];
    int tid = threadIdx.x;
    sa[tid] = (tid < NB_BUCK) ? bcnt[tid] : 0;
    __syncthreads();
    int* src = sa; int* dst = sb;
    for (int st = 1; st < 256; st <<= 1) {
        int v = src[tid];
        if (tid >= st) v += src[tid - st];
        dst[tid] = v;
        __syncthreads();
        int* t = src; src = dst; dst = t;
    }
    if (tid < NB_BUCK) {
        int ex = (tid == 0) ? 0 : src[tid - 1];
        bbase[tid] = ex;
        bcursor[tid] = ex;
    }
    if (tid == 0) {
        bbase[NB_BUCK] = N_EDGES;
        rowp[N_NODES] = N_EDGES;
    }
}

// ---------------- bin: scatter (src,dst) as int2 into bucket regions ----------------

__global__ void k_bin(const int* __restrict__ ei, int* __restrict__ bcursor,
                      int2* __restrict__ edges) {
    __shared__ int hist[NB_BUCK];
    __shared__ int hbase[NB_BUCK];
    __shared__ int lcur[NB_BUCK];
    int tid = threadIdx.x;
    if (tid < NB_BUCK) { hist[tid] = 0; lcur[tid] = 0; }
    __syncthreads();
    int e0 = blockIdx.x * BIN_CHUNK;
    int e1 = min(e0 + BIN_CHUNK, N_EDGES);
    for (int e = e0 + tid; e < e1; e += 256) {
        int d = ei[N_EDGES + e];
        atomicAdd(&hist[d >> BUCK_SHIFT], 1);
    }
    __syncthreads();
    if (tid < NB_BUCK) {
        int h = hist[tid];
        hbase[tid] = (h > 0) ? atomicAdd(&bcursor[tid], h) : 0;
    }
    __syncthreads();
    for (int e = e0 + tid; e < e1; e += 256) {
        int s = ei[e];
        int d = ei[N_EDGES + e];
        int b = d >> BUCK_SHIFT;
        int off = atomicAdd(&lcur[b], 1);
        edges[hbase[b] + off] = make_int2(s, d);
    }
}

// ---------------- fill: per-bucket degree, rowp, dinv, CSR col ----------------

__global__ void k_fill(const int* __restrict__ bbase, const int2* __restrict__ edges,
                       int* __restrict__ rowp, float* __restrict__ dinv,
                       int* __restrict__ col) {
    __shared__ int ldeg[BUCK_SIZE];
    __shared__ int sa[BUCK_SIZE];
    __shared__ int sb[BUCK_SIZE];
    __shared__ int lcur[BUCK_SIZE];
    int b = blockIdx.x;
    int tid = threadIdx.x;
    int base_node = b << BUCK_SHIFT;
    int nn = min(BUCK_SIZE, N_NODES - base_node);
    int seg0 = bbase[b];
    int seg1 = bbase[b + 1];
    ldeg[tid] = 0;
    __syncthreads();
    for (int e = seg0 + tid; e < seg1; e += BUCK_SIZE) {
        atomicAdd(&ldeg[edges[e].y - base_node], 1);
    }
    __syncthreads();
    sa[tid] = ldeg[tid];
    __syncthreads();
    int* src = sa; int* dst = sb;
    for (int st = 1; st < BUCK_SIZE; st <<= 1) {
        int v = src[tid];
        if (tid >= st) v += src[tid - st];
        dst[tid] = v;
        __syncthreads();
        int* t = src; src = dst; dst = t;
    }
    int ex = (tid == 0) ? 0 : src[tid - 1];
    int rp = seg0 + ex;
    lcur[tid] = rp;
    if (tid < nn) {
        rowp[base_node + tid] = rp;
        dinv[base_node + tid] = rsqrtf((float)(ldeg[tid] + 1));
    }
    __syncthreads();
    for (int e = seg0 + tid; e < seg1; e += BUCK_SIZE) {
        int2 sd = edges[e];
        int p = atomicAdd(&lcur[sd.y - base_node], 1);
        col[p] = sd.x;
    }
}

// ---------------- layer-1 aggregate-first: XA = A_norm X  (f32, 35 ch) ----------------
// 1 node per 64-lane wave, lanes 0..34 = channels.

__global__ void k_conv35(const float* __restrict__ X, const int* __restrict__ rowp,
                         const int* __restrict__ col, const float* __restrict__ dinv,
                         float* __restrict__ XA) {
    int node = blockIdx.x * 4 + (threadIdx.x >> 6);
    int lane = threadIdx.x & 63;
    if (node >= N_NODES) return;
    int rp0 = rowp[node], rp1 = rowp[node + 1];
    float di = dinv[node];
    bool act = lane < IN_CH;
    float acc = act ? di * X[(size_t)node * IN_CH + lane] : 0.0f;
    int e = rp0;
    for (; e + 2 <= rp1; e += 2) {
        int s0 = col[e], s1 = col[e + 1];
        float d0 = dinv[s0], d1 = dinv[s1];
        if (act) {
            float x0 = X[(size_t)s0 * IN_CH + lane];
            float x1 = X[(size_t)s1 * IN_CH + lane];
            acc = fmaf(d0, x0, acc);
            acc = fmaf(d1, x1, acc);
        }
    }
    if (e < rp1 && act) {
        int s = col[e];
        acc = fmaf(dinv[s], X[(size_t)s * IN_CH + lane], acc);
    }
    if (act) XA[(size_t)node * IN_CH + lane] = di * acc;
}

// ---------------- GEMM1: Y1 = XA @ W1 + b1 -> bf16 ----------------

__global__ void k_gemm35(const float* __restrict__ X, const float* __restrict__ W,
                         const float* __restrict__ bias, unsigned* __restrict__ Yb) {
    __shared__ float xs[32 * IN_CH];
    int tid = threadIdx.x;
    int row0 = blockIdx.x * 32;
    for (int idx = tid; idx < 32 * IN_CH; idx += 256) {
        int r = idx / IN_CH;
        int k = idx - r * IN_CH;
        int gr = row0 + r;
        xs[idx] = (gr < N_NODES) ? X[(size_t)gr * IN_CH + k] : 0.0f;
    }
    __syncthreads();
    int tx = tid & 31, ty = tid >> 5;
    float acc[4][4] = {};
    for (int k = 0; k < IN_CH; ++k) {
        float4 w = *(const float4*)&W[k * HID + tx * 4];
        #pragma unroll
        for (int rr = 0; rr < 4; ++rr) {
            float x = xs[(ty * 4 + rr) * IN_CH + k];
            acc[rr][0] = fmaf(x, w.x, acc[rr][0]);
            acc[rr][1] = fmaf(x, w.y, acc[rr][1]);
            acc[rr][2] = fmaf(x, w.z, acc[rr][2]);
            acc[rr][3] = fmaf(x, w.w, acc[rr][3]);
        }
    }
    float4 bq = *(const float4*)&bias[tx * 4];
    #pragma unroll
    for (int rr = 0; rr < 4; ++rr) {
        int gr = row0 + ty * 4 + rr;
        if (gr < N_NODES) {
            unsigned lo = packbf2(acc[rr][0] + bq.x, acc[rr][1] + bq.y);
            unsigned hi = packbf2(acc[rr][2] + bq.z, acc[rr][3] + bq.w);
            *(uint2*)&Yb[(size_t)gr * 64 + tx * 2] = make_uint2(lo, hi);
        }
    }
}

// ---------------- GEMM2/3: H = gelu(BN(Y)) @ W -> bf16 (no bias) ----------------

__global__ void k_gemm128(const unsigned* __restrict__ Yb, const float* __restrict__ stats,
                          const float* __restrict__ g, const float* __restrict__ be,
                          const float* __restrict__ W, unsigned* __restrict__ Hb) {
    __shared__ float xs[32 * HID];
    __shared__ float sc_s[HID];
    __shared__ float sh_s[HID];
    int tid = threadIdx.x;
    if (tid < HID) {
        const float inv_n = 1.0f / (float)N_NODES;
        float mean = stats[tid] * inv_n;
        float var = stats[HID + tid] * inv_n - mean * mean;
        float s = g[tid] * rsqrtf(var + BN_EPS);
        sc_s[tid] = s;
        sh_s[tid] = be[tid] - mean * s;
    }
    __syncthreads();
    int row0 = blockIdx.x * 32;
    for (int u = tid; u < 32 * 64; u += 256) {
        int r = u >> 6, p = u & 63;
        int gr = row0 + r;
        float lo = 0.0f, hi = 0.0f;
        if (gr < N_NODES) {
            unsigned v = Yb[(size_t)gr * 64 + p];
            lo = gelu_f(fmaf(bflo(v), sc_s[2 * p], sh_s[2 * p]));
            hi = gelu_f(fmaf(bfhi(v), sc_s[2 * p + 1], sh_s[2 * p + 1]));
        }
        xs[r * HID + 2 * p]     = lo;
        xs[r * HID + 2 * p + 1] = hi;
    }
    __syncthreads();
    int tx = tid & 31, ty = tid >> 5;
    float acc[4][4] = {};
    for (int k = 0; k < HID; ++k) {
        float4 w = *(const float4*)&W[k * HID + tx * 4];
        #pragma unroll
        for (int rr = 0; rr < 4; ++rr) {
            float x = xs[(ty * 4 + rr) * HID + k];
            acc[rr][0] = fmaf(x, w.x, acc[rr][0]);
            acc[rr][1] = fmaf(x, w.y, acc[rr][1]);
            acc[rr][2] = fmaf(x, w.z, acc[rr][2]);
            acc[rr][3] = fmaf(x, w.w, acc[rr][3]);
        }
    }
    #pragma unroll
    for (int rr = 0; rr < 4; ++rr) {
        int gr = row0 + ty * 4 + rr;
        if (gr < N_NODES) {
            unsigned lo = packbf2(acc[rr][0], acc[rr][1]);
            unsigned hi = packbf2(acc[rr][2], acc[rr][3]);
            *(uint2*)&Hb[(size_t)gr * 64 + tx * 2] = make_uint2(lo, hi);
        }
    }
}

// ---------------- conv (bf16 gather): Y = di*(sum dinv_s H_s + di*H_i) + b ----------------
// 1 node per 64-lane wave, lane handles channels 2l, 2l+1 via one 4B load.

__global__ void k_convb(const unsigned* __restrict__ Hb, const int* __restrict__ rowp,
                        const int* __restrict__ col, const float* __restrict__ dinv,
                        const float* __restrict__ bias, unsigned* __restrict__ Yb) {
    int node = blockIdx.x * 4 + (threadIdx.x >> 6);
    int lane = threadIdx.x & 63;
    if (node >= N_NODES) return;
    int rp0 = rowp[node], rp1 = rowp[node + 1];
    float di = dinv[node];
    unsigned v = Hb[(size_t)node * 64 + lane];
    float a0 = di * bflo(v);
    float a1 = di * bfhi(v);
    int e = rp0;
    for (; e + 4 <= rp1; e += 4) {
        int s0 = col[e], s1 = col[e + 1], s2 = col[e + 2], s3 = col[e + 3];
        float d0 = dinv[s0], d1 = dinv[s1], d2 = dinv[s2], d3 = dinv[s3];
        unsigned v0 = Hb[(size_t)s0 * 64 + lane];
        unsigned v1 = Hb[(size_t)s1 * 64 + lane];
        unsigned v2 = Hb[(size_t)s2 * 64 + lane];
        unsigned v3 = Hb[(size_t)s3 * 64 + lane];
        a0 = fmaf(d0, bflo(v0), a0); a1 = fmaf(d0, bfhi(v0), a1);
        a0 = fmaf(d1, bflo(v1), a0); a1 = fmaf(d1, bfhi(v1), a1);
        a0 = fmaf(d2, bflo(v2), a0); a1 = fmaf(d2, bfhi(v2), a1);
        a0 = fmaf(d3, bflo(v3), a0); a1 = fmaf(d3, bfhi(v3), a1);
    }
    for (; e < rp1; ++e) {
        int s = col[e];
        float d = dinv[s];
        unsigned w = Hb[(size_t)s * 64 + lane];
        a0 = fmaf(d, bflo(w), a0);
        a1 = fmaf(d, bfhi(w), a1);
    }
    float y0 = fmaf(di, a0, bias[2 * lane]);
    float y1 = fmaf(di, a1, bias[2 * lane + 1]);
    Yb[(size_t)node * 64 + lane] = packbf2(y0, y1);
}

// ---------------- BN stats over bf16 Y ----------------

__global__ void k_statsb(const unsigned* __restrict__ Yb, float* __restrict__ stats) {
    __shared__ float ls[128];
    __shared__ float lss[128];
    int tid = threadIdx.x;
    int lane = tid & 63, grp = tid >> 6;
    if (tid < 128) { ls[tid] = 0.0f; lss[tid] = 0.0f; }
    __syncthreads();
    float s0 = 0, s1 = 0, q0 = 0, q1 = 0;
    for (int r = blockIdx.x * 4 + grp; r < N_NODES; r += gridDim.x * 4) {
        unsigned v = Yb[(size_t)r * 64 + lane];
        float lo = bflo(v), hi = bfhi(v);
        s0 += lo; q0 = fmaf(lo, lo, q0);
        s1 += hi; q1 = fmaf(hi, hi, q1);
    }
    atomicAdd(&ls[2 * lane], s0);
    atomicAdd(&ls[2 * lane + 1], s1);
    atomicAdd(&lss[2 * lane], q0);
    atomicAdd(&lss[2 * lane + 1], q1);
    __syncthreads();
    if (tid < 128) {
        atomicAdd(&stats[tid], ls[tid]);
        atomicAdd(&stats[128 + tid], lss[tid]);
    }
}

// ---------------- fused pool + MLP head (reads bf16 Y, applies BN+GELU) ----------------

__device__ __forceinline__ int lowerb(const int* __restrict__ arr, int n, int key) {
    int lo = 0, hi = n;
    while (lo < hi) {
        int mid = (lo + hi) >> 1;
        if (arr[mid] < key) lo = mid + 1; else hi = mid;
    }
    return lo;
}

__global__ void k_pool_mlp(const unsigned* __restrict__ Yb, const float* __restrict__ stats,
                           const float* __restrict__ g, const float* __restrict__ be,
                           const int* __restrict__ batch,
                           const float* __restrict__ Wl1, const float* __restrict__ bl1,
                           const float* __restrict__ Wl2, const float* __restrict__ bl2,
                           float* __restrict__ out) {
    __shared__ float pooled[128];
    __shared__ float sc_s[128];
    __shared__ float sh_s[128];
    __shared__ int bounds[2];
    int gidx = blockIdx.x;
    int tid = threadIdx.x;
    if (tid < 128) {
        const float inv_n = 1.0f / (float)N_NODES;
        float mean = stats[tid] * inv_n;
        float var = stats[128 + tid] * inv_n - mean * mean;
        float s = g[tid] * rsqrtf(var + BN_EPS);
        sc_s[tid] = s;
        sh_s[tid] = be[tid] - mean * s;
    }
    if (tid == 0) {
        bounds[0] = lowerb(batch, N_NODES, gidx);
        bounds[1] = lowerb(batch, N_NODES, gidx + 1);
    }
    __syncthreads();
    int lo = bounds[0], hi = bounds[1];
    float s = sc_s[tid], h = sh_s[tid];
    int half = tid & 1;
    int word = tid >> 1;
    float acc = 0.0f;
    for (int r = lo; r < hi; ++r) {
        unsigned v = Yb[(size_t)r * 64 + word];
        float x = half ? bfhi(v) : bflo(v);
        acc += gelu_f(fmaf(x, s, h));
    }
    pooled[tid] = (hi > lo) ? acc / (float)(hi - lo) : 0.0f;
    __syncthreads();
    if (tid < 64) {
        float hs = bl1[tid];
        #pragma unroll 4
        for (int k = 0; k < 128; ++k)
            hs = fmaf(pooled[k], Wl1[k * 64 + tid], hs);
        float e = (hs > 0.0f) ? hs : expm1f(hs);
        float part = e * Wl2[tid];
        #pragma unroll
        for (int o = 32; o > 0; o >>= 1)
            part += __shfl_down(part, o);
        if (tid == 0) out[gidx] = part + bl2[0];
    }
}

// ---------------- host launch ----------------

extern "C" void kernel_launch(void* const* d_in, const int* in_sizes, int n_in,
                              void* d_out, int out_size, void* d_ws, size_t ws_size,
                              hipStream_t stream) {
    const float* x   = (const float*)d_in[0];
    const int*   ei  = (const int*)d_in[1];
    const int*   bat = (const int*)d_in[2];
    const float* W1  = (const float*)d_in[3];
    const float* b1  = (const float*)d_in[4];
    const float* g1  = (const float*)d_in[5];
    const float* be1 = (const float*)d_in[6];
    const float* W2  = (const float*)d_in[7];
    const float* b2  = (const float*)d_in[8];
    const float* g2  = (const float*)d_in[9];
    const float* be2 = (const float*)d_in[10];
    const float* W3  = (const float*)d_in[11];
    const float* b3  = (const float*)d_in[12];
    const float* g3  = (const float*)d_in[13];
    const float* be3 = (const float*)d_in[14];
    const float* Wl1 = (const float*)d_in[15];
    const float* bl1 = (const float*)d_in[16];
    const float* Wl2 = (const float*)d_in[17];
    const float* bl2 = (const float*)d_in[18];
    float* out = (float*)d_out;

    char* ws = (char*)d_ws;
    size_t off = 0;
    auto alloc = [&](size_t bytes) -> char* {
        char* p = ws + off;
        off += (bytes + 255) & ~(size_t)255;
        return p;
    };
    int*      bcnt    = (int*)alloc(NB_BUCK * sizeof(int));
    int*      bbase   = (int*)alloc((NB_BUCK + 1) * sizeof(int));
    int*      bcursor = (int*)alloc(NB_BUCK * sizeof(int));
    int2*     edges   = (int2*)alloc((size_t)N_EDGES * sizeof(int2));
    int*      rowp    = (int*)alloc((N_NODES + 1) * sizeof(int));
    float*    dinv    = (float*)alloc(N_NODES * sizeof(float));
    int*      col     = (int*)alloc((size_t)N_EDGES * sizeof(int));
    float*    XA      = (float*)alloc((size_t)N_NODES * IN_CH * sizeof(float));
    unsigned* Ybuf    = (unsigned*)alloc((size_t)N_NODES * 64 * sizeof(unsigned));
    unsigned* Hbuf    = (unsigned*)alloc((size_t)N_NODES * 64 * sizeof(unsigned));
    float*    stats   = (float*)alloc(3 * 256 * sizeof(float));

    // ---- graph structure ----
    k_zero2<<<1, 1024, 0, stream>>>(bcnt, stats);
    k_bhist<<<BIN_GRID, 256, 0, stream>>>(ei, bcnt);
    k_bscan<<<1, 256, 0, stream>>>(bcnt, bbase, bcursor, rowp);
    k_bin<<<BIN_GRID, 256, 0, stream>>>(ei, bcursor, edges);
    k_fill<<<NB_BUCK, BUCK_SIZE, 0, stream>>>(bbase, edges, rowp, dinv, col);

    const int gemm_blocks = (N_NODES + 31) / 32;
    const int conv_blocks = (N_NODES + 3) / 4;

    // ---- layer 1 (aggregate-first) ----
    k_conv35<<<conv_blocks, 256, 0, stream>>>(x, rowp, col, dinv, XA);
    k_gemm35<<<gemm_blocks, 256, 0, stream>>>(XA, W1, b1, Ybuf);
    k_statsb<<<1024, 256, 0, stream>>>(Ybuf, stats + 0 * 256);

    // ---- layer 2 ----
    k_gemm128<<<gemm_blocks, 256, 0, stream>>>(Ybuf, stats + 0 * 256, g1, be1, W2, Hbuf);
    k_convb<<<conv_blocks, 256, 0, stream>>>(Hbuf, rowp, col, dinv, b2, Ybuf);
    k_statsb<<<1024, 256, 0, stream>>>(Ybuf, stats + 1 * 256);

    // ---- layer 3 ----
    k_gemm128<<<gemm_blocks, 256, 0, stream>>>(Ybuf, stats + 1 * 256, g2, be2, W3, Hbuf);
    k_convb<<<conv_blocks, 256, 0, stream>>>(Hbuf, rowp, col, dinv, b3, Ybuf);
    k_statsb<<<1024, 256, 0, stream>>>(Ybuf, stats + 2 * 256);

    // ---- pool + head ----
    k_pool_mlp<<<NUM_GRAPHS, 128, 0, stream>>>(Ybuf, stats + 2 * 256, g3, be3, bat,
                                               Wl1, bl1, Wl2, bl2, out);
}

// Round 4
// 887.188 us; speedup vs baseline: 1.9816x; 1.4185x over previous
//
#include <hip/hip_runtime.h>
#include <hip/hip_bf16.h>
#include <math.h>

#define N_NODES 100000
#define N_EDGES 3200000
#define NUM_GRAPHS 2048
#define IN_CH 35
#define HID 128
#define BN_EPS 1e-5f

#define BUCK_SHIFT 9
#define BUCK_SIZE 512
#define NB_BUCK 196          // ceil(100000/512)
#define BIN_GRID 1024
#define BIN_CHUNK 3125       // ceil(3200000/1024)

__device__ __forceinline__ float gelu_f(float x) {
    return 0.5f * x * (1.0f + erff(x * 0.70710678118654752440f));
}

// bf16 helpers: packed 2 x bf16 in a uint (lo = even channel, hi = odd channel)
__device__ __forceinline__ float bflo(unsigned v) { return __uint_as_float(v << 16); }
__device__ __forceinline__ float bfhi(unsigned v) { return __uint_as_float(v & 0xffff0000u); }
__device__ __forceinline__ unsigned f2bf(float f) {
    unsigned x = __float_as_uint(f);
    return (x + 0x7fffu + ((x >> 16) & 1u)) >> 16;   // RNE
}
__device__ __forceinline__ unsigned packbf2(float lo, float hi) {
    return f2bf(lo) | (f2bf(hi) << 16);
}

// ---------------- zero bucket counters + stats ----------------

__global__ void k_zero2(int* __restrict__ bcnt, float* __restrict__ stats) {
    int i = threadIdx.x;
    if (i < NB_BUCK) bcnt[i] = 0;
    if (i < 3 * 256) stats[i] = 0.0f;
}

// ---------------- bucket histogram (LDS-aggregated) ----------------

__global__ void k_bhist(const int* __restrict__ ei, int* __restrict__ bcnt) {
    __shared__ int hist[NB_BUCK];
    int tid = threadIdx.x;
    if (tid < NB_BUCK) hist[tid] = 0;
    __syncthreads();
    int e0 = blockIdx.x * BIN_CHUNK;
    int e1 = min(e0 + BIN_CHUNK, N_EDGES);
    for (int e = e0 + tid; e < e1; e += 256) {
        int d = ei[N_EDGES + e];
        atomicAdd(&hist[d >> BUCK_SHIFT], 1);
    }
    __syncthreads();
    if (tid < NB_BUCK && hist[tid] > 0) atomicAdd(&bcnt[tid], hist[tid]);
}

// ---------------- bucket scan ----------------

__global__ void k_bscan(const int* __restrict__ bcnt, int* __restrict__ bbase,
                        int* __restrict__ bcursor, int* __restrict__ rowp) {
    __shared__ int sa[256];
    __shared__ int sb[256];
    int tid = threadIdx.x;
    sa[tid] = (tid < NB_BUCK) ? bcnt[tid] : 0;
    __syncthreads();
    int* src = sa; int* dst = sb;
    for (int st = 1; st < 256; st <<= 1) {
        int v = src[tid];
        if (tid >= st) v += src[tid - st];
        dst[tid] = v;
        __syncthreads();
        int* t = src; src = dst; dst = t;
    }
    if (tid < NB_BUCK) {
        int ex = (tid == 0) ? 0 : src[tid - 1];
        bbase[tid] = ex;
        bcursor[tid] = ex;
    }
    if (tid == 0) {
        bbase[NB_BUCK] = N_EDGES;
        rowp[N_NODES] = N_EDGES;
    }
}

// ---------------- bin: scatter (src,dst) as int2 into bucket regions ----------------

__global__ void k_bin(const int* __restrict__ ei, int* __restrict__ bcursor,
                      int2* __restrict__ edges) {
    __shared__ int hist[NB_BUCK];
    __shared__ int hbase[NB_BUCK];
    __shared__ int lcur[NB_BUCK];
    int tid = threadIdx.x;
    if (tid < NB_BUCK) { hist[tid] = 0; lcur[tid] = 0; }
    __syncthreads();
    int e0 = blockIdx.x * BIN_CHUNK;
    int e1 = min(e0 + BIN_CHUNK, N_EDGES);
    for (int e = e0 + tid; e < e1; e += 256) {
        int d = ei[N_EDGES + e];
        atomicAdd(&hist[d >> BUCK_SHIFT], 1);
    }
    __syncthreads();
    if (tid < NB_BUCK) {
        int h = hist[tid];
        hbase[tid] = (h > 0) ? atomicAdd(&bcursor[tid], h) : 0;
    }
    __syncthreads();
    for (int e = e0 + tid; e < e1; e += 256) {
        int s = ei[e];
        int d = ei[N_EDGES + e];
        int b = d >> BUCK_SHIFT;
        int off = atomicAdd(&lcur[b], 1);
        edges[hbase[b] + off] = make_int2(s, d);
    }
}

// ---------------- fill: per-bucket degree, rowp, dinv, CSR col ----------------

__global__ void k_fill(const int* __restrict__ bbase, const int2* __restrict__ edges,
                       int* __restrict__ rowp, float* __restrict__ dinv,
                       int* __restrict__ col) {
    __shared__ int ldeg[BUCK_SIZE];
    __shared__ int sa[BUCK_SIZE];
    __shared__ int sb[BUCK_SIZE];
    __shared__ int lcur[BUCK_SIZE];
    int b = blockIdx.x;
    int tid = threadIdx.x;
    int base_node = b << BUCK_SHIFT;
    int nn = min(BUCK_SIZE, N_NODES - base_node);
    int seg0 = bbase[b];
    int seg1 = bbase[b + 1];
    ldeg[tid] = 0;
    __syncthreads();
    for (int e = seg0 + tid; e < seg1; e += BUCK_SIZE) {
        atomicAdd(&ldeg[edges[e].y - base_node], 1);
    }
    __syncthreads();
    sa[tid] = ldeg[tid];
    __syncthreads();
    int* src = sa; int* dst = sb;
    for (int st = 1; st < BUCK_SIZE; st <<= 1) {
        int v = src[tid];
        if (tid >= st) v += src[tid - st];
        dst[tid] = v;
        __syncthreads();
        int* t = src; src = dst; dst = t;
    }
    int ex = (tid == 0) ? 0 : src[tid - 1];
    int rp = seg0 + ex;
    lcur[tid] = rp;
    if (tid < nn) {
        rowp[base_node + tid] = rp;
        dinv[base_node + tid] = rsqrtf((float)(ldeg[tid] + 1));
    }
    __syncthreads();
    for (int e = seg0 + tid; e < seg1; e += BUCK_SIZE) {
        int2 sd = edges[e];
        int p = atomicAdd(&lcur[sd.y - base_node], 1);
        col[p] = sd.x;
    }
}

// ---------------- cast X -> bf16 rows padded to 32 uints (128 B) ----------------

__global__ void k_castx(const float* __restrict__ X, unsigned* __restrict__ Xb) {
    int i = blockIdx.x * blockDim.x + threadIdx.x;
    if (i >= N_NODES * 32) return;
    int n = i >> 5, j = i & 31;
    float lo = 0.0f, hi = 0.0f;
    if (j < 17) {
        lo = X[(size_t)n * IN_CH + 2 * j];
        hi = X[(size_t)n * IN_CH + 2 * j + 1];
    } else if (j == 17) {
        lo = X[(size_t)n * IN_CH + 34];
    }
    Xb[i] = packbf2(lo, hi);
}

// ---------------- fused layer-1: Y1 = (A_norm Xb) W1 + b1 -> bf16 ----------------
// 512 threads = 8 waves = 8 nodes per block. Each wave: halves gather alternate
// edges (bf16 rows, 128 B aligned), __shfl-combine, XA row -> LDS, then the
// 35x128 GEMM out of LDS-staged W1.

#define C1_NODES 8

__global__ __launch_bounds__(512) void k_conv1(
        const unsigned* __restrict__ Xb, const int* __restrict__ rowp,
        const int* __restrict__ col, const float* __restrict__ dinv,
        const float* __restrict__ W1, const float* __restrict__ b1,
        unsigned* __restrict__ Yb) {
    __shared__ float w_s[IN_CH * HID];       // 17.9 KB
    __shared__ float b_s[HID];
    __shared__ float xa_s[C1_NODES][36];
    int tid = threadIdx.x;
    for (int u = tid; u < IN_CH * HID; u += 512) w_s[u] = W1[u];
    if (tid < HID) b_s[tid] = b1[tid];

    int wid = tid >> 6;
    int lane = tid & 63;
    int half = lane >> 5;
    int l = lane & 31;
    int node = blockIdx.x * C1_NODES + wid;
    bool valid = node < N_NODES;

    float a0 = 0.0f, a1 = 0.0f;
    float di = 0.0f;
    if (valid) {
        int rp0 = rowp[node], rp1 = rowp[node + 1];
        di = dinv[node];
        if (half == 0) {
            unsigned v = Xb[(size_t)node * 32 + l];
            a0 = di * bflo(v);
            a1 = di * bfhi(v);
        }
        int e = rp0 + half;
        for (; e + 2 < rp1; e += 4) {         // 2 edges per half-iter
            int s0 = col[e], s1 = col[e + 2];
            float d0 = dinv[s0], d1 = dinv[s1];
            unsigned v0 = Xb[(size_t)s0 * 32 + l];
            unsigned v1 = Xb[(size_t)s1 * 32 + l];
            a0 = fmaf(d0, bflo(v0), a0); a1 = fmaf(d0, bfhi(v0), a1);
            a0 = fmaf(d1, bflo(v1), a0); a1 = fmaf(d1, bfhi(v1), a1);
        }
        if (e < rp1) {
            int s = col[e];
            float d = dinv[s];
            unsigned v = Xb[(size_t)s * 32 + l];
            a0 = fmaf(d, bflo(v), a0);
            a1 = fmaf(d, bfhi(v), a1);
        }
    }
    // combine halves (partner exchange)
    a0 += __shfl(a0, (lane + 32) & 63, 64);
    a1 += __shfl(a1, (lane + 32) & 63, 64);
    if (valid && half == 0 && l < 18) {
        xa_s[wid][2 * l]     = di * a0;
        xa_s[wid][2 * l + 1] = di * a1;
    }
    __syncthreads();
    // GEMM phase: wave wid computes node wid's 128 outputs, 2 cols/lane
    float acc0 = b_s[2 * lane];
    float acc1 = b_s[2 * lane + 1];
    #pragma unroll 7
    for (int k = 0; k < IN_CH; ++k) {
        float xv = xa_s[wid][k];
        acc0 = fmaf(xv, w_s[k * HID + 2 * lane], acc0);
        acc1 = fmaf(xv, w_s[k * HID + 2 * lane + 1], acc1);
    }
    if (valid) Yb[(size_t)node * 64 + lane] = packbf2(acc0, acc1);
}

// ---------------- GEMM2/3: H = gelu(BN(Y)) @ W -> bf16 (no bias) ----------------

__global__ void k_gemm128(const unsigned* __restrict__ Yb, const float* __restrict__ stats,
                          const float* __restrict__ g, const float* __restrict__ be,
                          const float* __restrict__ W, unsigned* __restrict__ Hb) {
    __shared__ float xs[32 * HID];
    __shared__ float sc_s[HID];
    __shared__ float sh_s[HID];
    int tid = threadIdx.x;
    if (tid < HID) {
        const float inv_n = 1.0f / (float)N_NODES;
        float mean = stats[tid] * inv_n;
        float var = stats[HID + tid] * inv_n - mean * mean;
        float s = g[tid] * rsqrtf(var + BN_EPS);
        sc_s[tid] = s;
        sh_s[tid] = be[tid] - mean * s;
    }
    __syncthreads();
    int row0 = blockIdx.x * 32;
    for (int u = tid; u < 32 * 64; u += 256) {
        int r = u >> 6, p = u & 63;
        int gr = row0 + r;
        float lo = 0.0f, hi = 0.0f;
        if (gr < N_NODES) {
            unsigned v = Yb[(size_t)gr * 64 + p];
            lo = gelu_f(fmaf(bflo(v), sc_s[2 * p], sh_s[2 * p]));
            hi = gelu_f(fmaf(bfhi(v), sc_s[2 * p + 1], sh_s[2 * p + 1]));
        }
        xs[r * HID + 2 * p]     = lo;
        xs[r * HID + 2 * p + 1] = hi;
    }
    __syncthreads();
    int tx = tid & 31, ty = tid >> 5;
    float acc[4][4] = {};
    for (int k = 0; k < HID; ++k) {
        float4 w = *(const float4*)&W[k * HID + tx * 4];
        #pragma unroll
        for (int rr = 0; rr < 4; ++rr) {
            float x = xs[(ty * 4 + rr) * HID + k];
            acc[rr][0] = fmaf(x, w.x, acc[rr][0]);
            acc[rr][1] = fmaf(x, w.y, acc[rr][1]);
            acc[rr][2] = fmaf(x, w.z, acc[rr][2]);
            acc[rr][3] = fmaf(x, w.w, acc[rr][3]);
        }
    }
    #pragma unroll
    for (int rr = 0; rr < 4; ++rr) {
        int gr = row0 + ty * 4 + rr;
        if (gr < N_NODES) {
            unsigned lo = packbf2(acc[rr][0], acc[rr][1]);
            unsigned hi = packbf2(acc[rr][2], acc[rr][3]);
            *(uint2*)&Hb[(size_t)gr * 64 + tx * 2] = make_uint2(lo, hi);
        }
    }
}

// ---------------- conv (bf16 gather): Y = di*(sum dinv_s H_s + di*H_i) + b ----------------

__global__ void k_convb(const unsigned* __restrict__ Hb, const int* __restrict__ rowp,
                        const int* __restrict__ col, const float* __restrict__ dinv,
                        const float* __restrict__ bias, unsigned* __restrict__ Yb) {
    int node = blockIdx.x * 4 + (threadIdx.x >> 6);
    int lane = threadIdx.x & 63;
    if (node >= N_NODES) return;
    int rp0 = rowp[node], rp1 = rowp[node + 1];
    float di = dinv[node];
    unsigned v = Hb[(size_t)node * 64 + lane];
    float a0 = di * bflo(v);
    float a1 = di * bfhi(v);
    int e = rp0;
    for (; e + 4 <= rp1; e += 4) {
        int s0 = col[e], s1 = col[e + 1], s2 = col[e + 2], s3 = col[e + 3];
        float d0 = dinv[s0], d1 = dinv[s1], d2 = dinv[s2], d3 = dinv[s3];
        unsigned v0 = Hb[(size_t)s0 * 64 + lane];
        unsigned v1 = Hb[(size_t)s1 * 64 + lane];
        unsigned v2 = Hb[(size_t)s2 * 64 + lane];
        unsigned v3 = Hb[(size_t)s3 * 64 + lane];
        a0 = fmaf(d0, bflo(v0), a0); a1 = fmaf(d0, bfhi(v0), a1);
        a0 = fmaf(d1, bflo(v1), a0); a1 = fmaf(d1, bfhi(v1), a1);
        a0 = fmaf(d2, bflo(v2), a0); a1 = fmaf(d2, bfhi(v2), a1);
        a0 = fmaf(d3, bflo(v3), a0); a1 = fmaf(d3, bfhi(v3), a1);
    }
    for (; e < rp1; ++e) {
        int s = col[e];
        float d = dinv[s];
        unsigned w = Hb[(size_t)s * 64 + lane];
        a0 = fmaf(d, bflo(w), a0);
        a1 = fmaf(d, bfhi(w), a1);
    }
    float y0 = fmaf(di, a0, bias[2 * lane]);
    float y1 = fmaf(di, a1, bias[2 * lane + 1]);
    Yb[(size_t)node * 64 + lane] = packbf2(y0, y1);
}

// ---------------- BN stats over bf16 Y ----------------

__global__ void k_statsb(const unsigned* __restrict__ Yb, float* __restrict__ stats) {
    __shared__ float ls[128];
    __shared__ float lss[128];
    int tid = threadIdx.x;
    int lane = tid & 63, grp = tid >> 6;
    if (tid < 128) { ls[tid] = 0.0f; lss[tid] = 0.0f; }
    __syncthreads();
    float s0 = 0, s1 = 0, q0 = 0, q1 = 0;
    for (int r = blockIdx.x * 4 + grp; r < N_NODES; r += gridDim.x * 4) {
        unsigned v = Yb[(size_t)r * 64 + lane];
        float lo = bflo(v), hi = bfhi(v);
        s0 += lo; q0 = fmaf(lo, lo, q0);
        s1 += hi; q1 = fmaf(hi, hi, q1);
    }
    atomicAdd(&ls[2 * lane], s0);
    atomicAdd(&ls[2 * lane + 1], s1);
    atomicAdd(&lss[2 * lane], q0);
    atomicAdd(&lss[2 * lane + 1], q1);
    __syncthreads();
    if (tid < 128) {
        atomicAdd(&stats[tid], ls[tid]);
        atomicAdd(&stats[128 + tid], lss[tid]);
    }
}

// ---------------- fused pool + MLP head ----------------

__device__ __forceinline__ int lowerb(const int* __restrict__ arr, int n, int key) {
    int lo = 0, hi = n;
    while (lo < hi) {
        int mid = (lo + hi) >> 1;
        if (arr[mid] < key) lo = mid + 1; else hi = mid;
    }
    return lo;
}

__global__ void k_pool_mlp(const unsigned* __restrict__ Yb, const float* __restrict__ stats,
                           const float* __restrict__ g, const float* __restrict__ be,
                           const int* __restrict__ batch,
                           const float* __restrict__ Wl1, const float* __restrict__ bl1,
                           const float* __restrict__ Wl2, const float* __restrict__ bl2,
                           float* __restrict__ out) {
    __shared__ float pooled[128];
    __shared__ float sc_s[128];
    __shared__ float sh_s[128];
    __shared__ int bounds[2];
    int gidx = blockIdx.x;
    int tid = threadIdx.x;
    if (tid < 128) {
        const float inv_n = 1.0f / (float)N_NODES;
        float mean = stats[tid] * inv_n;
        float var = stats[128 + tid] * inv_n - mean * mean;
        float s = g[tid] * rsqrtf(var + BN_EPS);
        sc_s[tid] = s;
        sh_s[tid] = be[tid] - mean * s;
    }
    if (tid == 0) {
        bounds[0] = lowerb(batch, N_NODES, gidx);
        bounds[1] = lowerb(batch, N_NODES, gidx + 1);
    }
    __syncthreads();
    int lo = bounds[0], hi = bounds[1];
    float s = sc_s[tid], h = sh_s[tid];
    int half = tid & 1;
    int word = tid >> 1;
    float acc = 0.0f;
    for (int r = lo; r < hi; ++r) {
        unsigned v = Yb[(size_t)r * 64 + word];
        float x = half ? bfhi(v) : bflo(v);
        acc += gelu_f(fmaf(x, s, h));
    }
    pooled[tid] = (hi > lo) ? acc / (float)(hi - lo) : 0.0f;
    __syncthreads();
    if (tid < 64) {
        float hs = bl1[tid];
        #pragma unroll 4
        for (int k = 0; k < 128; ++k)
            hs = fmaf(pooled[k], Wl1[k * 64 + tid], hs);
        float e = (hs > 0.0f) ? hs : expm1f(hs);
        float part = e * Wl2[tid];
        #pragma unroll
        for (int o = 32; o > 0; o >>= 1)
            part += __shfl_down(part, o);
        if (tid == 0) out[gidx] = part + bl2[0];
    }
}

// ---------------- host launch ----------------

extern "C" void kernel_launch(void* const* d_in, const int* in_sizes, int n_in,
                              void* d_out, int out_size, void* d_ws, size_t ws_size,
                              hipStream_t stream) {
    const float* x   = (const float*)d_in[0];
    const int*   ei  = (const int*)d_in[1];
    const int*   bat = (const int*)d_in[2];
    const float* W1  = (const float*)d_in[3];
    const float* b1  = (const float*)d_in[4];
    const float* g1  = (const float*)d_in[5];
    const float* be1 = (const float*)d_in[6];
    const float* W2  = (const float*)d_in[7];
    const float* b2  = (const float*)d_in[8];
    const float* g2  = (const float*)d_in[9];
    const float* be2 = (const float*)d_in[10];
    const float* W3  = (const float*)d_in[11];
    const float* b3  = (const float*)d_in[12];
    const float* g3  = (const float*)d_in[13];
    const float* be3 = (const float*)d_in[14];
    const float* Wl1 = (const float*)d_in[15];
    const float* bl1 = (const float*)d_in[16];
    const float* Wl2 = (const float*)d_in[17];
    const float* bl2 = (const float*)d_in[18];
    float* out = (float*)d_out;

    char* ws = (char*)d_ws;
    size_t off = 0;
    auto alloc = [&](size_t bytes) -> char* {
        char* p = ws + off;
        off += (bytes + 255) & ~(size_t)255;
        return p;
    };
    int*      bcnt    = (int*)alloc(NB_BUCK * sizeof(int));
    int*      bbase   = (int*)alloc((NB_BUCK + 1) * sizeof(int));
    int*      bcursor = (int*)alloc(NB_BUCK * sizeof(int));
    int2*     edges   = (int2*)alloc((size_t)N_EDGES * sizeof(int2));
    int*      rowp    = (int*)alloc((N_NODES + 1) * sizeof(int));
    float*    dinv    = (float*)alloc(N_NODES * sizeof(float));
    int*      col     = (int*)alloc((size_t)N_EDGES * sizeof(int));
    unsigned* Xb      = (unsigned*)alloc((size_t)N_NODES * 32 * sizeof(unsigned));
    unsigned* Ybuf    = (unsigned*)alloc((size_t)N_NODES * 64 * sizeof(unsigned));
    unsigned* Hbuf    = (unsigned*)alloc((size_t)N_NODES * 64 * sizeof(unsigned));
    float*    stats   = (float*)alloc(3 * 256 * sizeof(float));

    // ---- graph structure + X cast ----
    k_zero2<<<1, 1024, 0, stream>>>(bcnt, stats);
    k_bhist<<<BIN_GRID, 256, 0, stream>>>(ei, bcnt);
    k_bscan<<<1, 256, 0, stream>>>(bcnt, bbase, bcursor, rowp);
    k_bin<<<BIN_GRID, 256, 0, stream>>>(ei, bcursor, edges);
    k_fill<<<NB_BUCK, BUCK_SIZE, 0, stream>>>(bbase, edges, rowp, dinv, col);
    k_castx<<<(N_NODES * 32 + 255) / 256, 256, 0, stream>>>(x, Xb);

    const int gemm_blocks = (N_NODES + 31) / 32;
    const int conv_blocks = (N_NODES + 3) / 4;

    // ---- layer 1 (fused aggregate + GEMM) ----
    k_conv1<<<(N_NODES + C1_NODES - 1) / C1_NODES, 512, 0, stream>>>(
        Xb, rowp, col, dinv, W1, b1, Ybuf);
    k_statsb<<<1024, 256, 0, stream>>>(Ybuf, stats + 0 * 256);

    // ---- layer 2 ----
    k_gemm128<<<gemm_blocks, 256, 0, stream>>>(Ybuf, stats + 0 * 256, g1, be1, W2, Hbuf);
    k_convb<<<conv_blocks, 256, 0, stream>>>(Hbuf, rowp, col, dinv, b2, Ybuf);
    k_statsb<<<1024, 256, 0, stream>>>(Ybuf, stats + 1 * 256);

    // ---- layer 3 ----
    k_gemm128<<<gemm_blocks, 256, 0, stream>>>(Ybuf, stats + 1 * 256, g2, be2, W3, Hbuf);
    k_convb<<<conv_blocks, 256, 0, stream>>>(Hbuf, rowp, col, dinv, b3, Ybuf);
    k_statsb<<<1024, 256, 0, stream>>>(Ybuf, stats + 2 * 256);

    // ---- pool + head ----
    k_pool_mlp<<<NUM_GRAPHS, 128, 0, stream>>>(Ybuf, stats + 2 * 256, g3, be3, bat,
                                               Wl1, bl1, Wl2, bl2, out);
}

// Round 5
// 832.253 us; speedup vs baseline: 2.1124x; 1.0660x over previous
//
#include <hip/hip_runtime.h>
#include <hip/hip_bf16.h>
#include <math.h>

#define N_NODES 100000
#define N_EDGES 3200000
#define NUM_GRAPHS 2048
#define IN_CH 35
#define HID 128
#define BN_EPS 1e-5f

#define BUCK_SHIFT 9
#define BUCK_SIZE 512
#define NB_BUCK 196          // ceil(100000/512)
#define BIN_GRID 1024
#define BIN_CHUNK 3125       // ceil(3200000/1024)

__device__ __forceinline__ float gelu_f(float x) {
    return 0.5f * x * (1.0f + erff(x * 0.70710678118654752440f));
}

// bf16 helpers: packed 2 x bf16 in a uint (lo = even channel, hi = odd channel)
__device__ __forceinline__ float bflo(unsigned v) { return __uint_as_float(v << 16); }
__device__ __forceinline__ float bfhi(unsigned v) { return __uint_as_float(v & 0xffff0000u); }
__device__ __forceinline__ unsigned f2bf(float f) {
    unsigned x = __float_as_uint(f);
    return (x + 0x7fffu + ((x >> 16) & 1u)) >> 16;   // RNE
}
__device__ __forceinline__ unsigned packbf2(float lo, float hi) {
    return f2bf(lo) | (f2bf(hi) << 16);
}

// ---------------- zero bucket counters + stats ----------------

__global__ void k_zero2(int* __restrict__ bcnt, float* __restrict__ stats) {
    int i = threadIdx.x;
    if (i < NB_BUCK) bcnt[i] = 0;
    if (i < 3 * 256) stats[i] = 0.0f;
}

// ---------------- bucket histogram (LDS-aggregated) ----------------

__global__ void k_bhist(const int* __restrict__ ei, int* __restrict__ bcnt) {
    __shared__ int hist[NB_BUCK];
    int tid = threadIdx.x;
    if (tid < NB_BUCK) hist[tid] = 0;
    __syncthreads();
    int e0 = blockIdx.x * BIN_CHUNK;
    int e1 = min(e0 + BIN_CHUNK, N_EDGES);
    for (int e = e0 + tid; e < e1; e += 256) {
        int d = ei[N_EDGES + e];
        atomicAdd(&hist[d >> BUCK_SHIFT], 1);
    }
    __syncthreads();
    if (tid < NB_BUCK && hist[tid] > 0) atomicAdd(&bcnt[tid], hist[tid]);
}

// ---------------- bucket scan ----------------

__global__ void k_bscan(const int* __restrict__ bcnt, int* __restrict__ bbase,
                        int* __restrict__ bcursor, int* __restrict__ rowp) {
    __shared__ int sa[256];
    __shared__ int sb[256];
    int tid = threadIdx.x;
    sa[tid] = (tid < NB_BUCK) ? bcnt[tid] : 0;
    __syncthreads();
    int* src = sa; int* dst = sb;
    for (int st = 1; st < 256; st <<= 1) {
        int v = src[tid];
        if (tid >= st) v += src[tid - st];
        dst[tid] = v;
        __syncthreads();
        int* t = src; src = dst; dst = t;
    }
    if (tid < NB_BUCK) {
        int ex = (tid == 0) ? 0 : src[tid - 1];
        bbase[tid] = ex;
        bcursor[tid] = ex;
    }
    if (tid == 0) {
        bbase[NB_BUCK] = N_EDGES;
        rowp[N_NODES] = N_EDGES;
    }
}

// ---------------- bin: scatter (src,dst) as int2 into bucket regions ----------------

__global__ void k_bin(const int* __restrict__ ei, int* __restrict__ bcursor,
                      int2* __restrict__ edges) {
    __shared__ int hist[NB_BUCK];
    __shared__ int hbase[NB_BUCK];
    __shared__ int lcur[NB_BUCK];
    int tid = threadIdx.x;
    if (tid < NB_BUCK) { hist[tid] = 0; lcur[tid] = 0; }
    __syncthreads();
    int e0 = blockIdx.x * BIN_CHUNK;
    int e1 = min(e0 + BIN_CHUNK, N_EDGES);
    for (int e = e0 + tid; e < e1; e += 256) {
        int d = ei[N_EDGES + e];
        atomicAdd(&hist[d >> BUCK_SHIFT], 1);
    }
    __syncthreads();
    if (tid < NB_BUCK) {
        int h = hist[tid];
        hbase[tid] = (h > 0) ? atomicAdd(&bcursor[tid], h) : 0;
    }
    __syncthreads();
    for (int e = e0 + tid; e < e1; e += 256) {
        int s = ei[e];
        int d = ei[N_EDGES + e];
        int b = d >> BUCK_SHIFT;
        int off = atomicAdd(&lcur[b], 1);
        edges[hbase[b] + off] = make_int2(s, d);
    }
}

// ---------------- fill: per-bucket degree, rowp, dinv, CSR col ----------------

__global__ void k_fill(const int* __restrict__ bbase, const int2* __restrict__ edges,
                       int* __restrict__ rowp, float* __restrict__ dinv,
                       int* __restrict__ col) {
    __shared__ int ldeg[BUCK_SIZE];
    __shared__ int sa[BUCK_SIZE];
    __shared__ int sb[BUCK_SIZE];
    __shared__ int lcur[BUCK_SIZE];
    int b = blockIdx.x;
    int tid = threadIdx.x;
    int base_node = b << BUCK_SHIFT;
    int nn = min(BUCK_SIZE, N_NODES - base_node);
    int seg0 = bbase[b];
    int seg1 = bbase[b + 1];
    ldeg[tid] = 0;
    __syncthreads();
    for (int e = seg0 + tid; e < seg1; e += BUCK_SIZE) {
        atomicAdd(&ldeg[edges[e].y - base_node], 1);
    }
    __syncthreads();
    sa[tid] = ldeg[tid];
    __syncthreads();
    int* src = sa; int* dst = sb;
    for (int st = 1; st < BUCK_SIZE; st <<= 1) {
        int v = src[tid];
        if (tid >= st) v += src[tid - st];
        dst[tid] = v;
        __syncthreads();
        int* t = src; src = dst; dst = t;
    }
    int ex = (tid == 0) ? 0 : src[tid - 1];
    int rp = seg0 + ex;
    lcur[tid] = rp;
    if (tid < nn) {
        rowp[base_node + tid] = rp;
        dinv[base_node + tid] = rsqrtf((float)(ldeg[tid] + 1));
    }
    __syncthreads();
    for (int e = seg0 + tid; e < seg1; e += BUCK_SIZE) {
        int2 sd = edges[e];
        int p = atomicAdd(&lcur[sd.y - base_node], 1);
        col[p] = sd.x;
    }
}

// ---------------- cast X -> bf16 rows padded to 32 uints (128 B) ----------------

__global__ void k_castx(const float* __restrict__ X, unsigned* __restrict__ Xb) {
    int i = blockIdx.x * blockDim.x + threadIdx.x;
    if (i >= N_NODES * 32) return;
    int n = i >> 5, j = i & 31;
    float lo = 0.0f, hi = 0.0f;
    if (j < 17) {
        lo = X[(size_t)n * IN_CH + 2 * j];
        hi = X[(size_t)n * IN_CH + 2 * j + 1];
    } else if (j == 17) {
        lo = X[(size_t)n * IN_CH + 34];
    }
    Xb[i] = packbf2(lo, hi);
}

// ---------------- fused layer-1: Y1 = (A_norm Xb) W1 + b1 -> bf16 ----------------
// 512 threads = 8 waves = 8 nodes/block. Wave = 4 groups x 16 lanes; group g
// owns edges e0+g (+4), lane j loads uint2 -> 16 lanes cover the 128 B row.
// 8 edges in flight per wave. Cross-group 2-shuffle reduce, XA -> LDS, then
// 35x128 GEMM tail from LDS-staged W1.

#define C1_NODES 8

__global__ __launch_bounds__(512) void k_conv1(
        const unsigned* __restrict__ Xb, const int* __restrict__ rowp,
        const int* __restrict__ col, const float* __restrict__ dinv,
        const float* __restrict__ W1, const float* __restrict__ b1,
        unsigned* __restrict__ Yb) {
    __shared__ float w_s[IN_CH * HID];       // 17.9 KB
    __shared__ float b_s[HID];
    __shared__ float xa_s[C1_NODES][36];
    int tid = threadIdx.x;
    for (int u = tid; u < IN_CH * HID; u += 512) w_s[u] = W1[u];
    if (tid < HID) b_s[tid] = b1[tid];

    int wid = tid >> 6;
    int lane = tid & 63;
    int g = lane >> 4;
    int j = lane & 15;
    int node = blockIdx.x * C1_NODES + wid;
    bool valid = node < N_NODES;

    float a0 = 0.0f, a1 = 0.0f, a2 = 0.0f, a3 = 0.0f;
    float di = 0.0f;
    if (valid) {
        int rp0 = rowp[node], rp1 = rowp[node + 1];
        di = dinv[node];
        uint2 sv = *(const uint2*)(Xb + (size_t)node * 32 + j * 2);
        float w0 = (g == 0) ? di : 0.0f;
        a0 = w0 * bflo(sv.x); a1 = w0 * bfhi(sv.x);
        a2 = w0 * bflo(sv.y); a3 = w0 * bfhi(sv.y);
        for (int e0 = rp0; e0 < rp1; e0 += 8) {
            int ea = e0 + g;
            int eb = e0 + g + 4;
            int eac = min(ea, rp1 - 1);
            int ebc = min(eb, rp1 - 1);
            int sa = col[eac];
            int sb = col[ebc];
            float da = dinv[sa]; if (ea >= rp1) da = 0.0f;
            float db = dinv[sb]; if (eb >= rp1) db = 0.0f;
            uint2 va = *(const uint2*)(Xb + (size_t)sa * 32 + j * 2);
            uint2 vb = *(const uint2*)(Xb + (size_t)sb * 32 + j * 2);
            a0 = fmaf(da, bflo(va.x), a0); a1 = fmaf(da, bfhi(va.x), a1);
            a2 = fmaf(da, bflo(va.y), a2); a3 = fmaf(da, bfhi(va.y), a3);
            a0 = fmaf(db, bflo(vb.x), a0); a1 = fmaf(db, bfhi(vb.x), a1);
            a2 = fmaf(db, bflo(vb.y), a2); a3 = fmaf(db, bfhi(vb.y), a3);
        }
    }
    // cross-group reduce: 4 groups -> group 0
    a0 += __shfl(a0, (lane + 32) & 63, 64);
    a1 += __shfl(a1, (lane + 32) & 63, 64);
    a2 += __shfl(a2, (lane + 32) & 63, 64);
    a3 += __shfl(a3, (lane + 32) & 63, 64);
    a0 += __shfl(a0, (lane + 16) & 63, 64);
    a1 += __shfl(a1, (lane + 16) & 63, 64);
    a2 += __shfl(a2, (lane + 16) & 63, 64);
    a3 += __shfl(a3, (lane + 16) & 63, 64);
    if (valid && g == 0 && j < 9) {
        xa_s[wid][4 * j + 0] = di * a0;
        xa_s[wid][4 * j + 1] = di * a1;
        xa_s[wid][4 * j + 2] = di * a2;
        xa_s[wid][4 * j + 3] = di * a3;
    }
    __syncthreads();
    // GEMM tail: wave wid computes node's 128 outputs, 2 cols/lane
    float acc0 = b_s[2 * lane];
    float acc1 = b_s[2 * lane + 1];
    #pragma unroll 7
    for (int k = 0; k < IN_CH; ++k) {
        float xv = xa_s[wid][k];
        acc0 = fmaf(xv, w_s[k * HID + 2 * lane], acc0);
        acc1 = fmaf(xv, w_s[k * HID + 2 * lane + 1], acc1);
    }
    if (valid) Yb[(size_t)node * 64 + lane] = packbf2(acc0, acc1);
}

// ---------------- GEMM2/3: H = gelu(BN(Y)) @ W -> bf16 (no bias) ----------------

__global__ void k_gemm128(const unsigned* __restrict__ Yb, const float* __restrict__ stats,
                          const float* __restrict__ g, const float* __restrict__ be,
                          const float* __restrict__ W, unsigned* __restrict__ Hb) {
    __shared__ float xs[32 * HID];
    __shared__ float sc_s[HID];
    __shared__ float sh_s[HID];
    int tid = threadIdx.x;
    if (tid < HID) {
        const float inv_n = 1.0f / (float)N_NODES;
        float mean = stats[tid] * inv_n;
        float var = stats[HID + tid] * inv_n - mean * mean;
        float s = g[tid] * rsqrtf(var + BN_EPS);
        sc_s[tid] = s;
        sh_s[tid] = be[tid] - mean * s;
    }
    __syncthreads();
    int row0 = blockIdx.x * 32;
    for (int u = tid; u < 32 * 64; u += 256) {
        int r = u >> 6, p = u & 63;
        int gr = row0 + r;
        float lo = 0.0f, hi = 0.0f;
        if (gr < N_NODES) {
            unsigned v = Yb[(size_t)gr * 64 + p];
            lo = gelu_f(fmaf(bflo(v), sc_s[2 * p], sh_s[2 * p]));
            hi = gelu_f(fmaf(bfhi(v), sc_s[2 * p + 1], sh_s[2 * p + 1]));
        }
        xs[r * HID + 2 * p]     = lo;
        xs[r * HID + 2 * p + 1] = hi;
    }
    __syncthreads();
    int tx = tid & 31, ty = tid >> 5;
    float acc[4][4] = {};
    for (int k = 0; k < HID; ++k) {
        float4 w = *(const float4*)&W[k * HID + tx * 4];
        #pragma unroll
        for (int rr = 0; rr < 4; ++rr) {
            float x = xs[(ty * 4 + rr) * HID + k];
            acc[rr][0] = fmaf(x, w.x, acc[rr][0]);
            acc[rr][1] = fmaf(x, w.y, acc[rr][1]);
            acc[rr][2] = fmaf(x, w.z, acc[rr][2]);
            acc[rr][3] = fmaf(x, w.w, acc[rr][3]);
        }
    }
    #pragma unroll
    for (int rr = 0; rr < 4; ++rr) {
        int gr = row0 + ty * 4 + rr;
        if (gr < N_NODES) {
            unsigned lo = packbf2(acc[rr][0], acc[rr][1]);
            unsigned hi = packbf2(acc[rr][2], acc[rr][3]);
            *(uint2*)&Hb[(size_t)gr * 64 + tx * 2] = make_uint2(lo, hi);
        }
    }
}

// ---------------- conv (bf16 gather): Y = di*(sum dinv_s H_s + di*H_i) + b ----
// 256 threads = 4 waves = 4 nodes/block. Wave = 4 groups x 16 lanes; group g
// owns edges e0+g (+4); lane j loads uint4 (8 channels) -> 16 lanes cover the
// 256 B row. 8 edges in flight. Cross-group 2-shuffle reduce; group 0 writes.

__global__ void k_convb(const unsigned* __restrict__ Hb, const int* __restrict__ rowp,
                        const int* __restrict__ col, const float* __restrict__ dinv,
                        const float* __restrict__ bias, unsigned* __restrict__ Yb) {
    int tid = threadIdx.x;
    int wid = tid >> 6;
    int lane = tid & 63;
    int g = lane >> 4;
    int j = lane & 15;
    int node = blockIdx.x * 4 + wid;
    if (node >= N_NODES) return;
    int rp0 = rowp[node], rp1 = rowp[node + 1];
    float di = dinv[node];
    uint4 sv = *(const uint4*)(Hb + (size_t)node * 64 + j * 4);
    float w0 = (g == 0) ? di : 0.0f;
    float a0 = w0 * bflo(sv.x), a1 = w0 * bfhi(sv.x);
    float a2 = w0 * bflo(sv.y), a3 = w0 * bfhi(sv.y);
    float a4 = w0 * bflo(sv.z), a5 = w0 * bfhi(sv.z);
    float a6 = w0 * bflo(sv.w), a7 = w0 * bfhi(sv.w);
    for (int e0 = rp0; e0 < rp1; e0 += 8) {
        int ea = e0 + g;
        int eb = e0 + g + 4;
        int eac = min(ea, rp1 - 1);
        int ebc = min(eb, rp1 - 1);
        int sa = col[eac];
        int sb = col[ebc];
        float da = dinv[sa]; if (ea >= rp1) da = 0.0f;
        float db = dinv[sb]; if (eb >= rp1) db = 0.0f;
        uint4 va = *(const uint4*)(Hb + (size_t)sa * 64 + j * 4);
        uint4 vb = *(const uint4*)(Hb + (size_t)sb * 64 + j * 4);
        a0 = fmaf(da, bflo(va.x), a0); a1 = fmaf(da, bfhi(va.x), a1);
        a2 = fmaf(da, bflo(va.y), a2); a3 = fmaf(da, bfhi(va.y), a3);
        a4 = fmaf(da, bflo(va.z), a4); a5 = fmaf(da, bfhi(va.z), a5);
        a6 = fmaf(da, bflo(va.w), a6); a7 = fmaf(da, bfhi(va.w), a7);
        a0 = fmaf(db, bflo(vb.x), a0); a1 = fmaf(db, bfhi(vb.x), a1);
        a2 = fmaf(db, bflo(vb.y), a2); a3 = fmaf(db, bfhi(vb.y), a3);
        a4 = fmaf(db, bflo(vb.z), a4); a5 = fmaf(db, bfhi(vb.z), a5);
        a6 = fmaf(db, bflo(vb.w), a6); a7 = fmaf(db, bfhi(vb.w), a7);
    }
    a0 += __shfl(a0, (lane + 32) & 63, 64);
    a1 += __shfl(a1, (lane + 32) & 63, 64);
    a2 += __shfl(a2, (lane + 32) & 63, 64);
    a3 += __shfl(a3, (lane + 32) & 63, 64);
    a4 += __shfl(a4, (lane + 32) & 63, 64);
    a5 += __shfl(a5, (lane + 32) & 63, 64);
    a6 += __shfl(a6, (lane + 32) & 63, 64);
    a7 += __shfl(a7, (lane + 32) & 63, 64);
    a0 += __shfl(a0, (lane + 16) & 63, 64);
    a1 += __shfl(a1, (lane + 16) & 63, 64);
    a2 += __shfl(a2, (lane + 16) & 63, 64);
    a3 += __shfl(a3, (lane + 16) & 63, 64);
    a4 += __shfl(a4, (lane + 16) & 63, 64);
    a5 += __shfl(a5, (lane + 16) & 63, 64);
    a6 += __shfl(a6, (lane + 16) & 63, 64);
    a7 += __shfl(a7, (lane + 16) & 63, 64);
    if (g == 0) {
        float y0 = fmaf(di, a0, bias[8 * j + 0]);
        float y1 = fmaf(di, a1, bias[8 * j + 1]);
        float y2 = fmaf(di, a2, bias[8 * j + 2]);
        float y3 = fmaf(di, a3, bias[8 * j + 3]);
        float y4 = fmaf(di, a4, bias[8 * j + 4]);
        float y5 = fmaf(di, a5, bias[8 * j + 5]);
        float y6 = fmaf(di, a6, bias[8 * j + 6]);
        float y7 = fmaf(di, a7, bias[8 * j + 7]);
        uint4 o;
        o.x = packbf2(y0, y1);
        o.y = packbf2(y2, y3);
        o.z = packbf2(y4, y5);
        o.w = packbf2(y6, y7);
        *(uint4*)(Yb + (size_t)node * 64 + j * 4) = o;
    }
}

// ---------------- BN stats over bf16 Y ----------------

__global__ void k_statsb(const unsigned* __restrict__ Yb, float* __restrict__ stats) {
    __shared__ float ls[128];
    __shared__ float lss[128];
    int tid = threadIdx.x;
    int lane = tid & 63, grp = tid >> 6;
    if (tid < 128) { ls[tid] = 0.0f; lss[tid] = 0.0f; }
    __syncthreads();
    float s0 = 0, s1 = 0, q0 = 0, q1 = 0;
    for (int r = blockIdx.x * 4 + grp; r < N_NODES; r += gridDim.x * 4) {
        unsigned v = Yb[(size_t)r * 64 + lane];
        float lo = bflo(v), hi = bfhi(v);
        s0 += lo; q0 = fmaf(lo, lo, q0);
        s1 += hi; q1 = fmaf(hi, hi, q1);
    }
    atomicAdd(&ls[2 * lane], s0);
    atomicAdd(&ls[2 * lane + 1], s1);
    atomicAdd(&lss[2 * lane], q0);
    atomicAdd(&lss[2 * lane + 1], q1);
    __syncthreads();
    if (tid < 128) {
        atomicAdd(&stats[tid], ls[tid]);
        atomicAdd(&stats[128 + tid], lss[tid]);
    }
}

// ---------------- fused pool + MLP head ----------------

__device__ __forceinline__ int lowerb(const int* __restrict__ arr, int n, int key) {
    int lo = 0, hi = n;
    while (lo < hi) {
        int mid = (lo + hi) >> 1;
        if (arr[mid] < key) lo = mid + 1; else hi = mid;
    }
    return lo;
}

__global__ void k_pool_mlp(const unsigned* __restrict__ Yb, const float* __restrict__ stats,
                           const float* __restrict__ g, const float* __restrict__ be,
                           const int* __restrict__ batch,
                           const float* __restrict__ Wl1, const float* __restrict__ bl1,
                           const float* __restrict__ Wl2, const float* __restrict__ bl2,
                           float* __restrict__ out) {
    __shared__ float pooled[128];
    __shared__ float sc_s[128];
    __shared__ float sh_s[128];
    __shared__ int bounds[2];
    int gidx = blockIdx.x;
    int tid = threadIdx.x;
    if (tid < 128) {
        const float inv_n = 1.0f / (float)N_NODES;
        float mean = stats[tid] * inv_n;
        float var = stats[128 + tid] * inv_n - mean * mean;
        float s = g[tid] * rsqrtf(var + BN_EPS);
        sc_s[tid] = s;
        sh_s[tid] = be[tid] - mean * s;
    }
    if (tid == 0) {
        bounds[0] = lowerb(batch, N_NODES, gidx);
        bounds[1] = lowerb(batch, N_NODES, gidx + 1);
    }
    __syncthreads();
    int lo = bounds[0], hi = bounds[1];
    float s = sc_s[tid], h = sh_s[tid];
    int half = tid & 1;
    int word = tid >> 1;
    float acc = 0.0f;
    for (int r = lo; r < hi; ++r) {
        unsigned v = Yb[(size_t)r * 64 + word];
        float x = half ? bfhi(v) : bflo(v);
        acc += gelu_f(fmaf(x, s, h));
    }
    pooled[tid] = (hi > lo) ? acc / (float)(hi - lo) : 0.0f;
    __syncthreads();
    if (tid < 64) {
        float hs = bl1[tid];
        #pragma unroll 4
        for (int k = 0; k < 128; ++k)
            hs = fmaf(pooled[k], Wl1[k * 64 + tid], hs);
        float e = (hs > 0.0f) ? hs : expm1f(hs);
        float part = e * Wl2[tid];
        #pragma unroll
        for (int o = 32; o > 0; o >>= 1)
            part += __shfl_down(part, o);
        if (tid == 0) out[gidx] = part + bl2[0];
    }
}

// ---------------- host launch ----------------

extern "C" void kernel_launch(void* const* d_in, const int* in_sizes, int n_in,
                              void* d_out, int out_size, void* d_ws, size_t ws_size,
                              hipStream_t stream) {
    const float* x   = (const float*)d_in[0];
    const int*   ei  = (const int*)d_in[1];
    const int*   bat = (const int*)d_in[2];
    const float* W1  = (const float*)d_in[3];
    const float* b1  = (const float*)d_in[4];
    const float* g1  = (const float*)d_in[5];
    const float* be1 = (const float*)d_in[6];
    const float* W2  = (const float*)d_in[7];
    const float* b2  = (const float*)d_in[8];
    const float* g2  = (const float*)d_in[9];
    const float* be2 = (const float*)d_in[10];
    const float* W3  = (const float*)d_in[11];
    const float* b3  = (const float*)d_in[12];
    const float* g3  = (const float*)d_in[13];
    const float* be3 = (const float*)d_in[14];
    const float* Wl1 = (const float*)d_in[15];
    const float* bl1 = (const float*)d_in[16];
    const float* Wl2 = (const float*)d_in[17];
    const float* bl2 = (const float*)d_in[18];
    float* out = (float*)d_out;

    char* ws = (char*)d_ws;
    size_t off = 0;
    auto alloc = [&](size_t bytes) -> char* {
        char* p = ws + off;
        off += (bytes + 255) & ~(size_t)255;
        return p;
    };
    int*      bcnt    = (int*)alloc(NB_BUCK * sizeof(int));
    int*      bbase   = (int*)alloc((NB_BUCK + 1) * sizeof(int));
    int*      bcursor = (int*)alloc(NB_BUCK * sizeof(int));
    int2*     edges   = (int2*)alloc((size_t)N_EDGES * sizeof(int2));
    int*      rowp    = (int*)alloc((N_NODES + 1) * sizeof(int));
    float*    dinv    = (float*)alloc(N_NODES * sizeof(float));
    int*      col     = (int*)alloc((size_t)N_EDGES * sizeof(int));
    unsigned* Xb      = (unsigned*)alloc((size_t)N_NODES * 32 * sizeof(unsigned));
    unsigned* Ybuf    = (unsigned*)alloc((size_t)N_NODES * 64 * sizeof(unsigned));
    unsigned* Hbuf    = (unsigned*)alloc((size_t)N_NODES * 64 * sizeof(unsigned));
    float*    stats   = (float*)alloc(3 * 256 * sizeof(float));

    // ---- graph structure + X cast ----
    k_zero2<<<1, 1024, 0, stream>>>(bcnt, stats);
    k_bhist<<<BIN_GRID, 256, 0, stream>>>(ei, bcnt);
    k_bscan<<<1, 256, 0, stream>>>(bcnt, bbase, bcursor, rowp);
    k_bin<<<BIN_GRID, 256, 0, stream>>>(ei, bcursor, edges);
    k_fill<<<NB_BUCK, BUCK_SIZE, 0, stream>>>(bbase, edges, rowp, dinv, col);
    k_castx<<<(N_NODES * 32 + 255) / 256, 256, 0, stream>>>(x, Xb);

    const int gemm_blocks = (N_NODES + 31) / 32;
    const int conv_blocks = (N_NODES + 3) / 4;

    // ---- layer 1 (fused aggregate + GEMM) ----
    k_conv1<<<(N_NODES + C1_NODES - 1) / C1_NODES, 512, 0, stream>>>(
        Xb, rowp, col, dinv, W1, b1, Ybuf);
    k_statsb<<<1024, 256, 0, stream>>>(Ybuf, stats + 0 * 256);

    // ---- layer 2 ----
    k_gemm128<<<gemm_blocks, 256, 0, stream>>>(Ybuf, stats + 0 * 256, g1, be1, W2, Hbuf);
    k_convb<<<conv_blocks, 256, 0, stream>>>(Hbuf, rowp, col, dinv, b2, Ybuf);
    k_statsb<<<1024, 256, 0, stream>>>(Ybuf, stats + 1 * 256);

    // ---- layer 3 ----
    k_gemm128<<<gemm_blocks, 256, 0, stream>>>(Ybuf, stats + 1 * 256, g2, be2, W3, Hbuf);
    k_convb<<<conv_blocks, 256, 0, stream>>>(Hbuf, rowp, col, dinv, b3, Ybuf);
    k_statsb<<<1024, 256, 0, stream>>>(Ybuf, stats + 2 * 256);

    // ---- pool + head ----
    k_pool_mlp<<<NUM_GRAPHS, 128, 0, stream>>>(Ybuf, stats + 2 * 256, g3, be3, bat,
                                               Wl1, bl1, Wl2, bl2, out);
}

// Round 6
// 792.885 us; speedup vs baseline: 2.2173x; 1.0497x over previous
//
#include <hip/hip_runtime.h>
#include <hip/hip_bf16.h>
#include <math.h>

#define N_NODES 100000
#define N_EDGES 3200000
#define NUM_GRAPHS 2048
#define IN_CH 35
#define HID 128
#define BN_EPS 1e-5f

#define BUCK_SHIFT 9
#define BUCK_SIZE 512
#define NB_BUCK 196          // ceil(100000/512)
#define BIN_GRID 1024
#define BIN_CHUNK 3125       // ceil(3200000/1024)

__device__ __forceinline__ float gelu_f(float x) {
    return 0.5f * x * (1.0f + erff(x * 0.70710678118654752440f));
}

// bf16 helpers: packed 2 x bf16 in a uint (lo = even channel, hi = odd channel)
__device__ __forceinline__ float bflo(unsigned v) { return __uint_as_float(v << 16); }
__device__ __forceinline__ float bfhi(unsigned v) { return __uint_as_float(v & 0xffff0000u); }
__device__ __forceinline__ unsigned f2bf(float f) {
    unsigned x = __float_as_uint(f);
    return (x + 0x7fffu + ((x >> 16) & 1u)) >> 16;   // RNE
}
__device__ __forceinline__ unsigned packbf2(float lo, float hi) {
    return f2bf(lo) | (f2bf(hi) << 16);
}

// ---------------- zero bucket counters + stats + pad rows ----------------

__global__ void k_zero2(int* __restrict__ bcnt, float* __restrict__ stats,
                        unsigned* __restrict__ xzero, unsigned* __restrict__ hzero) {
    int i = threadIdx.x;
    if (i < NB_BUCK) bcnt[i] = 0;
    if (i < 3 * 256) stats[i] = 0.0f;
    if (i < 32) xzero[i] = 0u;   // Xb pad row (node N_NODES)
    if (i < 64) hzero[i] = 0u;   // Hb pad row (node N_NODES)
}

// ---------------- bucket histogram (LDS-aggregated) ----------------

__global__ void k_bhist(const int* __restrict__ ei, int* __restrict__ bcnt) {
    __shared__ int hist[NB_BUCK];
    int tid = threadIdx.x;
    if (tid < NB_BUCK) hist[tid] = 0;
    __syncthreads();
    int e0 = blockIdx.x * BIN_CHUNK;
    int e1 = min(e0 + BIN_CHUNK, N_EDGES);
    for (int e = e0 + tid; e < e1; e += 256) {
        int d = ei[N_EDGES + e];
        atomicAdd(&hist[d >> BUCK_SHIFT], 1);
    }
    __syncthreads();
    if (tid < NB_BUCK && hist[tid] > 0) atomicAdd(&bcnt[tid], hist[tid]);
}

// ---------------- bucket scan ----------------

__global__ void k_bscan(const int* __restrict__ bcnt, int* __restrict__ bbase,
                        int* __restrict__ bcursor, int* __restrict__ rowp) {
    __shared__ int sa[256];
    __shared__ int sb[256];
    int tid = threadIdx.x;
    sa[tid] = (tid < NB_BUCK) ? bcnt[tid] : 0;
    __syncthreads();
    int* src = sa; int* dst = sb;
    for (int st = 1; st < 256; st <<= 1) {
        int v = src[tid];
        if (tid >= st) v += src[tid - st];
        dst[tid] = v;
        __syncthreads();
        int* t = src; src = dst; dst = t;
    }
    if (tid < NB_BUCK) {
        int ex = (tid == 0) ? 0 : src[tid - 1];
        bbase[tid] = ex;
        bcursor[tid] = ex;
    }
    if (tid == 0) {
        bbase[NB_BUCK] = N_EDGES;
        rowp[N_NODES] = N_EDGES;
    }
}

// ---------------- bin: LDS-cached chunk scatter into bucket regions ----------------

__global__ void k_bin(const int* __restrict__ ei, int* __restrict__ bcursor,
                      int2* __restrict__ edges) {
    __shared__ int lsrc[BIN_CHUNK];
    __shared__ int ldst[BIN_CHUNK];
    __shared__ int hist[NB_BUCK];
    __shared__ int hbase[NB_BUCK];
    __shared__ int lcur[NB_BUCK];
    int tid = threadIdx.x;
    if (tid < NB_BUCK) { hist[tid] = 0; lcur[tid] = 0; }
    __syncthreads();
    int e0 = blockIdx.x * BIN_CHUNK;
    int nE = min(e0 + BIN_CHUNK, N_EDGES) - e0;
    for (int i = tid; i < nE; i += 256) {
        int s = ei[e0 + i];
        int d = ei[N_EDGES + e0 + i];
        lsrc[i] = s;
        ldst[i] = d;
        atomicAdd(&hist[d >> BUCK_SHIFT], 1);
    }
    __syncthreads();
    if (tid < NB_BUCK) {
        int h = hist[tid];
        hbase[tid] = (h > 0) ? atomicAdd(&bcursor[tid], h) : 0;
    }
    __syncthreads();
    for (int i = tid; i < nE; i += 256) {
        int d = ldst[i];
        int b = d >> BUCK_SHIFT;
        int off = atomicAdd(&lcur[b], 1);
        edges[hbase[b] + off] = make_int2(lsrc[i], d);
    }
}

// ---------------- fill: per-bucket degree, rowp, dinv, CSR col ----------------

__global__ void k_fill(const int* __restrict__ bbase, const int2* __restrict__ edges,
                       int* __restrict__ rowp, float* __restrict__ dinv,
                       int* __restrict__ col) {
    __shared__ int ldeg[BUCK_SIZE];
    __shared__ int sa[BUCK_SIZE];
    __shared__ int sb[BUCK_SIZE];
    __shared__ int lcur[BUCK_SIZE];
    int b = blockIdx.x;
    int tid = threadIdx.x;
    int base_node = b << BUCK_SHIFT;
    int nn = min(BUCK_SIZE, N_NODES - base_node);
    int seg0 = bbase[b];
    int seg1 = bbase[b + 1];
    ldeg[tid] = 0;
    __syncthreads();
    for (int e = seg0 + tid; e < seg1; e += BUCK_SIZE) {
        atomicAdd(&ldeg[edges[e].y - base_node], 1);
    }
    __syncthreads();
    sa[tid] = ldeg[tid];
    __syncthreads();
    int* src = sa; int* dst = sb;
    for (int st = 1; st < BUCK_SIZE; st <<= 1) {
        int v = src[tid];
        if (tid >= st) v += src[tid - st];
        dst[tid] = v;
        __syncthreads();
        int* t = src; src = dst; dst = t;
    }
    int ex = (tid == 0) ? 0 : src[tid - 1];
    int rp = seg0 + ex;
    lcur[tid] = rp;
    if (tid < nn) {
        rowp[base_node + tid] = rp;
        dinv[base_node + tid] = rsqrtf((float)(ldeg[tid] + 1));
    }
    __syncthreads();
    for (int e = seg0 + tid; e < seg1; e += BUCK_SIZE) {
        int2 sd = edges[e];
        int p = atomicAdd(&lcur[sd.y - base_node], 1);
        col[p] = sd.x;
    }
}

// ---------------- cast X -> pre-scaled bf16 rows: Xb[n] = dinv[n]*X[n] ----------------
// padded to 32 uints (128 B)

__global__ void k_castx(const float* __restrict__ X, const float* __restrict__ dinv,
                        unsigned* __restrict__ Xb) {
    int i = blockIdx.x * blockDim.x + threadIdx.x;
    if (i >= N_NODES * 32) return;
    int n = i >> 5, j = i & 31;
    float dv = dinv[n];
    float lo = 0.0f, hi = 0.0f;
    if (j < 17) {
        lo = X[(size_t)n * IN_CH + 2 * j];
        hi = X[(size_t)n * IN_CH + 2 * j + 1];
    } else if (j == 17) {
        lo = X[(size_t)n * IN_CH + 34];
    }
    Xb[i] = packbf2(dv * lo, dv * hi);
}

#define ACC8(v) { a0 += bflo(v.x); a1 += bfhi(v.x); a2 += bflo(v.y); a3 += bfhi(v.y); \
                  a4 += bflo(v.z); a5 += bfhi(v.z); a6 += bflo(v.w); a7 += bfhi(v.w); }
#define ACC4(v) { a0 += bflo(v.x); a1 += bfhi(v.x); a2 += bflo(v.y); a3 += bfhi(v.y); }

// ---------------- fused layer-1: Y1 = (A_norm X) W1 + b1 -> bf16 ----------------
// Xb rows pre-scaled by dinv: XA = di*(sum_e Xb'_s + Xb'_i). 8 waves = 8 nodes
// per block; wave = 4 groups x 16 lanes; group g owns contiguous 4-edge runs,
// indices via one int4 load; 16 edges in flight; OOB edges clamp to zero row.

#define C1_NODES 8

__global__ __launch_bounds__(512) void k_conv1(
        const unsigned* __restrict__ Xb, const int* __restrict__ rowp,
        const int* __restrict__ col, const float* __restrict__ dinv,
        const float* __restrict__ W1, const float* __restrict__ b1,
        unsigned* __restrict__ Yb) {
    __shared__ float w_s[IN_CH * HID];       // 17.9 KB
    __shared__ float b_s[HID];
    __shared__ float xa_s[C1_NODES][36];
    int tid = threadIdx.x;
    for (int u = tid; u < IN_CH * HID; u += 512) w_s[u] = W1[u];
    if (tid < HID) b_s[tid] = b1[tid];

    int wid = tid >> 6;
    int lane = tid & 63;
    int g = lane >> 4;
    int j = lane & 15;
    int node = blockIdx.x * C1_NODES + wid;
    bool valid = node < N_NODES;

    float a0 = 0.0f, a1 = 0.0f, a2 = 0.0f, a3 = 0.0f;
    float di = 0.0f;
    if (valid) {
        int rp0 = rowp[node], rp1 = rowp[node + 1];
        di = dinv[node];
        uint2 sv = *(const uint2*)(Xb + (size_t)node * 32 + j * 2);
        float w0 = (g == 0) ? 1.0f : 0.0f;
        a0 = w0 * bflo(sv.x); a1 = w0 * bfhi(sv.x);
        a2 = w0 * bflo(sv.y); a3 = w0 * bfhi(sv.y);
        unsigned deg = (unsigned)(rp1 - rp0);
        for (int e0 = (rp0 & ~3); e0 < rp1; e0 += 16) {
            int eb = e0 + 4 * g;
            int4 cs = *(const int4*)(col + eb);
            int s0 = ((unsigned)(eb + 0 - rp0) < deg) ? cs.x : N_NODES;
            int s1 = ((unsigned)(eb + 1 - rp0) < deg) ? cs.y : N_NODES;
            int s2 = ((unsigned)(eb + 2 - rp0) < deg) ? cs.z : N_NODES;
            int s3 = ((unsigned)(eb + 3 - rp0) < deg) ? cs.w : N_NODES;
            uint2 v0 = *(const uint2*)(Xb + (size_t)s0 * 32 + j * 2);
            uint2 v1 = *(const uint2*)(Xb + (size_t)s1 * 32 + j * 2);
            uint2 v2 = *(const uint2*)(Xb + (size_t)s2 * 32 + j * 2);
            uint2 v3 = *(const uint2*)(Xb + (size_t)s3 * 32 + j * 2);
            ACC4(v0); ACC4(v1); ACC4(v2); ACC4(v3);
        }
    }
    // cross-group reduce: 4 groups -> group 0
    a0 += __shfl(a0, (lane + 32) & 63, 64);
    a1 += __shfl(a1, (lane + 32) & 63, 64);
    a2 += __shfl(a2, (lane + 32) & 63, 64);
    a3 += __shfl(a3, (lane + 32) & 63, 64);
    a0 += __shfl(a0, (lane + 16) & 63, 64);
    a1 += __shfl(a1, (lane + 16) & 63, 64);
    a2 += __shfl(a2, (lane + 16) & 63, 64);
    a3 += __shfl(a3, (lane + 16) & 63, 64);
    if (valid && g == 0 && j < 9) {
        xa_s[wid][4 * j + 0] = di * a0;
        xa_s[wid][4 * j + 1] = di * a1;
        xa_s[wid][4 * j + 2] = di * a2;
        xa_s[wid][4 * j + 3] = di * a3;
    }
    __syncthreads();
    // GEMM tail: wave wid computes node's 128 outputs, 2 cols/lane
    float acc0 = b_s[2 * lane];
    float acc1 = b_s[2 * lane + 1];
    #pragma unroll 7
    for (int k = 0; k < IN_CH; ++k) {
        float xv = xa_s[wid][k];
        acc0 = fmaf(xv, w_s[k * HID + 2 * lane], acc0);
        acc1 = fmaf(xv, w_s[k * HID + 2 * lane + 1], acc1);
    }
    if (valid) Yb[(size_t)node * 64 + lane] = packbf2(acc0, acc1);
}

// ---------------- GEMM2/3: Hb = dinv[row] * (gelu(BN(Y)) @ W) -> bf16 ----------------

__global__ void k_gemm128(const unsigned* __restrict__ Yb, const float* __restrict__ stats,
                          const float* __restrict__ g, const float* __restrict__ be,
                          const float* __restrict__ W, const float* __restrict__ dinv,
                          unsigned* __restrict__ Hb) {
    __shared__ float xs[32 * HID];
    __shared__ float sc_s[HID];
    __shared__ float sh_s[HID];
    int tid = threadIdx.x;
    if (tid < HID) {
        const float inv_n = 1.0f / (float)N_NODES;
        float mean = stats[tid] * inv_n;
        float var = stats[HID + tid] * inv_n - mean * mean;
        float s = g[tid] * rsqrtf(var + BN_EPS);
        sc_s[tid] = s;
        sh_s[tid] = be[tid] - mean * s;
    }
    __syncthreads();
    int row0 = blockIdx.x * 32;
    for (int u = tid; u < 32 * 64; u += 256) {
        int r = u >> 6, p = u & 63;
        int gr = row0 + r;
        float lo = 0.0f, hi = 0.0f;
        if (gr < N_NODES) {
            unsigned v = Yb[(size_t)gr * 64 + p];
            lo = gelu_f(fmaf(bflo(v), sc_s[2 * p], sh_s[2 * p]));
            hi = gelu_f(fmaf(bfhi(v), sc_s[2 * p + 1], sh_s[2 * p + 1]));
        }
        xs[r * HID + 2 * p]     = lo;
        xs[r * HID + 2 * p + 1] = hi;
    }
    __syncthreads();
    int tx = tid & 31, ty = tid >> 5;
    float acc[4][4] = {};
    for (int k = 0; k < HID; ++k) {
        float4 w = *(const float4*)&W[k * HID + tx * 4];
        #pragma unroll
        for (int rr = 0; rr < 4; ++rr) {
            float x = xs[(ty * 4 + rr) * HID + k];
            acc[rr][0] = fmaf(x, w.x, acc[rr][0]);
            acc[rr][1] = fmaf(x, w.y, acc[rr][1]);
            acc[rr][2] = fmaf(x, w.z, acc[rr][2]);
            acc[rr][3] = fmaf(x, w.w, acc[rr][3]);
        }
    }
    #pragma unroll
    for (int rr = 0; rr < 4; ++rr) {
        int gr = row0 + ty * 4 + rr;
        if (gr < N_NODES) {
            float dv = dinv[gr];
            unsigned lo = packbf2(dv * acc[rr][0], dv * acc[rr][1]);
            unsigned hi = packbf2(dv * acc[rr][2], dv * acc[rr][3]);
            *(uint2*)&Hb[(size_t)gr * 64 + tx * 2] = make_uint2(lo, hi);
        }
    }
}

// ---------------- conv (pre-scaled bf16 gather): Y = di*(sum Hb'_s + Hb'_i) + b ----
// 4 waves = 4 nodes/block; wave = 4 groups x 16 lanes; group g owns contiguous
// 4-edge runs (one int4 index load); lane j loads uint4 -> 16 lanes cover 256 B
// row; 16 edges in flight; OOB edges clamp to zero pad row.

__global__ void k_convb(const unsigned* __restrict__ Hb, const int* __restrict__ rowp,
                        const int* __restrict__ col, const float* __restrict__ dinv,
                        const float* __restrict__ bias, unsigned* __restrict__ Yb) {
    int tid = threadIdx.x;
    int wid = tid >> 6;
    int lane = tid & 63;
    int g = lane >> 4;
    int j = lane & 15;
    int node = blockIdx.x * 4 + wid;
    if (node >= N_NODES) return;
    int rp0 = rowp[node], rp1 = rowp[node + 1];
    float di = dinv[node];
    uint4 sv = *(const uint4*)(Hb + (size_t)node * 64 + j * 4);
    float w0 = (g == 0) ? 1.0f : 0.0f;
    float a0 = w0 * bflo(sv.x), a1 = w0 * bfhi(sv.x);
    float a2 = w0 * bflo(sv.y), a3 = w0 * bfhi(sv.y);
    float a4 = w0 * bflo(sv.z), a5 = w0 * bfhi(sv.z);
    float a6 = w0 * bflo(sv.w), a7 = w0 * bfhi(sv.w);
    unsigned deg = (unsigned)(rp1 - rp0);
    for (int e0 = (rp0 & ~3); e0 < rp1; e0 += 16) {
        int eb = e0 + 4 * g;
        int4 cs = *(const int4*)(col + eb);
        int s0 = ((unsigned)(eb + 0 - rp0) < deg) ? cs.x : N_NODES;
        int s1 = ((unsigned)(eb + 1 - rp0) < deg) ? cs.y : N_NODES;
        int s2 = ((unsigned)(eb + 2 - rp0) < deg) ? cs.z : N_NODES;
        int s3 = ((unsigned)(eb + 3 - rp0) < deg) ? cs.w : N_NODES;
        uint4 v0 = *(const uint4*)(Hb + (size_t)s0 * 64 + j * 4);
        uint4 v1 = *(const uint4*)(Hb + (size_t)s1 * 64 + j * 4);
        uint4 v2 = *(const uint4*)(Hb + (size_t)s2 * 64 + j * 4);
        uint4 v3 = *(const uint4*)(Hb + (size_t)s3 * 64 + j * 4);
        ACC8(v0); ACC8(v1); ACC8(v2); ACC8(v3);
    }
    a0 += __shfl(a0, (lane + 32) & 63, 64);
    a1 += __shfl(a1, (lane + 32) & 63, 64);
    a2 += __shfl(a2, (lane + 32) & 63, 64);
    a3 += __shfl(a3, (lane + 32) & 63, 64);
    a4 += __shfl(a4, (lane + 32) & 63, 64);
    a5 += __shfl(a5, (lane + 32) & 63, 64);
    a6 += __shfl(a6, (lane + 32) & 63, 64);
    a7 += __shfl(a7, (lane + 32) & 63, 64);
    a0 += __shfl(a0, (lane + 16) & 63, 64);
    a1 += __shfl(a1, (lane + 16) & 63, 64);
    a2 += __shfl(a2, (lane + 16) & 63, 64);
    a3 += __shfl(a3, (lane + 16) & 63, 64);
    a4 += __shfl(a4, (lane + 16) & 63, 64);
    a5 += __shfl(a5, (lane + 16) & 63, 64);
    a6 += __shfl(a6, (lane + 16) & 63, 64);
    a7 += __shfl(a7, (lane + 16) & 63, 64);
    if (g == 0) {
        const float4* bp = (const float4*)(bias + 8 * j);
        float4 bA = bp[0], bB = bp[1];
        uint4 o;
        o.x = packbf2(fmaf(di, a0, bA.x), fmaf(di, a1, bA.y));
        o.y = packbf2(fmaf(di, a2, bA.z), fmaf(di, a3, bA.w));
        o.z = packbf2(fmaf(di, a4, bB.x), fmaf(di, a5, bB.y));
        o.w = packbf2(fmaf(di, a6, bB.z), fmaf(di, a7, bB.w));
        *(uint4*)(Yb + (size_t)node * 64 + j * 4) = o;
    }
}

// ---------------- BN stats over bf16 Y ----------------

__global__ void k_statsb(const unsigned* __restrict__ Yb, float* __restrict__ stats) {
    __shared__ float ls[128];
    __shared__ float lss[128];
    int tid = threadIdx.x;
    int lane = tid & 63, grp = tid >> 6;
    if (tid < 128) { ls[tid] = 0.0f; lss[tid] = 0.0f; }
    __syncthreads();
    float s0 = 0, s1 = 0, q0 = 0, q1 = 0;
    for (int r = blockIdx.x * 4 + grp; r < N_NODES; r += gridDim.x * 4) {
        unsigned v = Yb[(size_t)r * 64 + lane];
        float lo = bflo(v), hi = bfhi(v);
        s0 += lo; q0 = fmaf(lo, lo, q0);
        s1 += hi; q1 = fmaf(hi, hi, q1);
    }
    atomicAdd(&ls[2 * lane], s0);
    atomicAdd(&ls[2 * lane + 1], s1);
    atomicAdd(&lss[2 * lane], q0);
    atomicAdd(&lss[2 * lane + 1], q1);
    __syncthreads();
    if (tid < 128) {
        atomicAdd(&stats[tid], ls[tid]);
        atomicAdd(&stats[128 + tid], lss[tid]);
    }
}

// ---------------- fused pool + MLP head ----------------

__device__ __forceinline__ int lowerb(const int* __restrict__ arr, int n, int key) {
    int lo = 0, hi = n;
    while (lo < hi) {
        int mid = (lo + hi) >> 1;
        if (arr[mid] < key) lo = mid + 1; else hi = mid;
    }
    return lo;
}

__global__ void k_pool_mlp(const unsigned* __restrict__ Yb, const float* __restrict__ stats,
                           const float* __restrict__ g, const float* __restrict__ be,
                           const int* __restrict__ batch,
                           const float* __restrict__ Wl1, const float* __restrict__ bl1,
                           const float* __restrict__ Wl2, const float* __restrict__ bl2,
                           float* __restrict__ out) {
    __shared__ float pooled[128];
    __shared__ float sc_s[128];
    __shared__ float sh_s[128];
    __shared__ int bounds[2];
    int gidx = blockIdx.x;
    int tid = threadIdx.x;
    if (tid < 128) {
        const float inv_n = 1.0f / (float)N_NODES;
        float mean = stats[tid] * inv_n;
        float var = stats[128 + tid] * inv_n - mean * mean;
        float s = g[tid] * rsqrtf(var + BN_EPS);
        sc_s[tid] = s;
        sh_s[tid] = be[tid] - mean * s;
    }
    if (tid == 0) {
        bounds[0] = lowerb(batch, N_NODES, gidx);
        bounds[1] = lowerb(batch, N_NODES, gidx + 1);
    }
    __syncthreads();
    int lo = bounds[0], hi = bounds[1];
    float s = sc_s[tid], h = sh_s[tid];
    int half = tid & 1;
    int word = tid >> 1;
    float acc = 0.0f;
    for (int r = lo; r < hi; ++r) {
        unsigned v = Yb[(size_t)r * 64 + word];
        float x = half ? bfhi(v) : bflo(v);
        acc += gelu_f(fmaf(x, s, h));
    }
    pooled[tid] = (hi > lo) ? acc / (float)(hi - lo) : 0.0f;
    __syncthreads();
    if (tid < 64) {
        float hs = bl1[tid];
        #pragma unroll 4
        for (int k = 0; k < 128; ++k)
            hs = fmaf(pooled[k], Wl1[k * 64 + tid], hs);
        float e = (hs > 0.0f) ? hs : expm1f(hs);
        float part = e * Wl2[tid];
        #pragma unroll
        for (int o = 32; o > 0; o >>= 1)
            part += __shfl_down(part, o);
        if (tid == 0) out[gidx] = part + bl2[0];
    }
}

// ---------------- host launch ----------------

extern "C" void kernel_launch(void* const* d_in, const int* in_sizes, int n_in,
                              void* d_out, int out_size, void* d_ws, size_t ws_size,
                              hipStream_t stream) {
    const float* x   = (const float*)d_in[0];
    const int*   ei  = (const int*)d_in[1];
    const int*   bat = (const int*)d_in[2];
    const float* W1  = (const float*)d_in[3];
    const float* b1  = (const float*)d_in[4];
    const float* g1  = (const float*)d_in[5];
    const float* be1 = (const float*)d_in[6];
    const float* W2  = (const float*)d_in[7];
    const float* b2  = (const float*)d_in[8];
    const float* g2  = (const float*)d_in[9];
    const float* be2 = (const float*)d_in[10];
    const float* W3  = (const float*)d_in[11];
    const float* b3  = (const float*)d_in[12];
    const float* g3  = (const float*)d_in[13];
    const float* be3 = (const float*)d_in[14];
    const float* Wl1 = (const float*)d_in[15];
    const float* bl1 = (const float*)d_in[16];
    const float* Wl2 = (const float*)d_in[17];
    const float* bl2 = (const float*)d_in[18];
    float* out = (float*)d_out;

    char* ws = (char*)d_ws;
    size_t off = 0;
    auto alloc = [&](size_t bytes) -> char* {
        char* p = ws + off;
        off += (bytes + 255) & ~(size_t)255;
        return p;
    };
    int*      bcnt    = (int*)alloc(NB_BUCK * sizeof(int));
    int*      bbase   = (int*)alloc((NB_BUCK + 1) * sizeof(int));
    int*      bcursor = (int*)alloc(NB_BUCK * sizeof(int));
    int2*     edges   = (int2*)alloc((size_t)N_EDGES * sizeof(int2));
    int*      rowp    = (int*)alloc((N_NODES + 1) * sizeof(int));
    float*    dinv    = (float*)alloc(N_NODES * sizeof(float));
    int*      col     = (int*)alloc((size_t)N_EDGES * sizeof(int));
    unsigned* Xb      = (unsigned*)alloc((size_t)(N_NODES + 1) * 32 * sizeof(unsigned));
    unsigned* Ybuf    = (unsigned*)alloc((size_t)N_NODES * 64 * sizeof(unsigned));
    unsigned* Hbuf    = (unsigned*)alloc((size_t)(N_NODES + 1) * 64 * sizeof(unsigned));
    float*    stats   = (float*)alloc(3 * 256 * sizeof(float));

    // ---- graph structure + X cast ----
    k_zero2<<<1, 1024, 0, stream>>>(bcnt, stats, Xb + (size_t)N_NODES * 32,
                                    Hbuf + (size_t)N_NODES * 64);
    k_bhist<<<BIN_GRID, 256, 0, stream>>>(ei, bcnt);
    k_bscan<<<1, 256, 0, stream>>>(bcnt, bbase, bcursor, rowp);
    k_bin<<<BIN_GRID, 256, 0, stream>>>(ei, bcursor, edges);
    k_fill<<<NB_BUCK, BUCK_SIZE, 0, stream>>>(bbase, edges, rowp, dinv, col);
    k_castx<<<(N_NODES * 32 + 255) / 256, 256, 0, stream>>>(x, dinv, Xb);

    const int gemm_blocks = (N_NODES + 31) / 32;
    const int conv_blocks = (N_NODES + 3) / 4;

    // ---- layer 1 (fused aggregate + GEMM) ----
    k_conv1<<<(N_NODES + C1_NODES - 1) / C1_NODES, 512, 0, stream>>>(
        Xb, rowp, col, dinv, W1, b1, Ybuf);
    k_statsb<<<1024, 256, 0, stream>>>(Ybuf, stats + 0 * 256);

    // ---- layer 2 ----
    k_gemm128<<<gemm_blocks, 256, 0, stream>>>(Ybuf, stats + 0 * 256, g1, be1, W2, dinv, Hbuf);
    k_convb<<<conv_blocks, 256, 0, stream>>>(Hbuf, rowp, col, dinv, b2, Ybuf);
    k_statsb<<<1024, 256, 0, stream>>>(Ybuf, stats + 1 * 256);

    // ---- layer 3 ----
    k_gemm128<<<gemm_blocks, 256, 0, stream>>>(Ybuf, stats + 1 * 256, g2, be2, W3, dinv, Hbuf);
    k_convb<<<conv_blocks, 256, 0, stream>>>(Hbuf, rowp, col, dinv, b3, Ybuf);
    k_statsb<<<1024, 256, 0, stream>>>(Ybuf, stats + 2 * 256);

    // ---- pool + head ----
    k_pool_mlp<<<NUM_GRAPHS, 128, 0, stream>>>(Ybuf, stats + 2 * 256, g3, be3, bat,
                                               Wl1, bl1, Wl2, bl2, out);
}

// Round 7
// 740.530 us; speedup vs baseline: 2.3740x; 1.0707x over previous
//
#include <hip/hip_runtime.h>
#include <hip/hip_bf16.h>
#include <math.h>

#define N_NODES 100000
#define N_EDGES 3200000
#define NUM_GRAPHS 2048
#define IN_CH 35
#define HID 128
#define BN_EPS 1e-5f

#define BUCK_SHIFT 9
#define BUCK_SIZE 512
#define NB_BUCK 196          // ceil(100000/512)
#define BIN_GRID 1024
#define BIN_CHUNK 3125       // ceil(3200000/1024)

typedef short bf16x8 __attribute__((ext_vector_type(8)));
typedef float f32x4 __attribute__((ext_vector_type(4)));

__device__ __forceinline__ float gelu_f(float x) {
    return 0.5f * x * (1.0f + erff(x * 0.70710678118654752440f));
}

// bf16 helpers: packed 2 x bf16 in a uint (lo = even channel, hi = odd channel)
__device__ __forceinline__ float bflo(unsigned v) { return __uint_as_float(v << 16); }
__device__ __forceinline__ float bfhi(unsigned v) { return __uint_as_float(v & 0xffff0000u); }
__device__ __forceinline__ unsigned f2bf(float f) {
    unsigned x = __float_as_uint(f);
    return (x + 0x7fffu + ((x >> 16) & 1u)) >> 16;   // RNE
}
__device__ __forceinline__ unsigned packbf2(float lo, float hi) {
    return f2bf(lo) | (f2bf(hi) << 16);
}

// ---------------- zero bucket counters + stats + pad rows ----------------

__global__ void k_zero2(int* __restrict__ bcnt, float* __restrict__ stats,
                        unsigned* __restrict__ xzero, unsigned* __restrict__ hzero) {
    int i = threadIdx.x;
    if (i < NB_BUCK) bcnt[i] = 0;
    if (i < 3 * 256) stats[i] = 0.0f;
    if (i < 32) xzero[i] = 0u;   // Xb pad row (node N_NODES)
    if (i < 64) hzero[i] = 0u;   // Hb pad row (node N_NODES)
}

// ---------------- W2/W3 -> bf16 transposed Wt[n][k] (packed pairs along k) ----------------

__global__ void k_wcast(const float* __restrict__ W2, const float* __restrict__ W3,
                        unsigned* __restrict__ Wt2, unsigned* __restrict__ Wt3) {
    int t = blockIdx.x * 256 + threadIdx.x;
    if (t >= 2 * 8192) return;
    const float* W = (t < 8192) ? W2 : W3;
    unsigned* Wt = (t < 8192) ? Wt2 : Wt3;
    int i = t & 8191;
    int n = i >> 6, j = i & 63;
    Wt[n * 64 + j] = packbf2(W[(2 * j) * HID + n], W[(2 * j + 1) * HID + n]);
}

// ---------------- bucket histogram (LDS-aggregated) ----------------

__global__ void k_bhist(const int* __restrict__ ei, int* __restrict__ bcnt) {
    __shared__ int hist[NB_BUCK];
    int tid = threadIdx.x;
    if (tid < NB_BUCK) hist[tid] = 0;
    __syncthreads();
    int e0 = blockIdx.x * BIN_CHUNK;
    int e1 = min(e0 + BIN_CHUNK, N_EDGES);
    for (int e = e0 + tid; e < e1; e += 256) {
        int d = ei[N_EDGES + e];
        atomicAdd(&hist[d >> BUCK_SHIFT], 1);
    }
    __syncthreads();
    if (tid < NB_BUCK && hist[tid] > 0) atomicAdd(&bcnt[tid], hist[tid]);
}

// ---------------- bucket scan ----------------

__global__ void k_bscan(const int* __restrict__ bcnt, int* __restrict__ bbase,
                        int* __restrict__ bcursor, int* __restrict__ rowp) {
    __shared__ int sa[256];
    __shared__ int sb[256];
    int tid = threadIdx.x;
    sa[tid] = (tid < NB_BUCK) ? bcnt[tid] : 0;
    __syncthreads();
    int* src = sa; int* dst = sb;
    for (int st = 1; st < 256; st <<= 1) {
        int v = src[tid];
        if (tid >= st) v += src[tid - st];
        dst[tid] = v;
        __syncthreads();
        int* t = src; src = dst; dst = t;
    }
    if (tid < NB_BUCK) {
        int ex = (tid == 0) ? 0 : src[tid - 1];
        bbase[tid] = ex;
        bcursor[tid] = ex;
    }
    if (tid == 0) {
        bbase[NB_BUCK] = N_EDGES;
        rowp[N_NODES] = N_EDGES;
    }
}

// ---------------- bin: LDS-cached chunk scatter into bucket regions ----------------

__global__ void k_bin(const int* __restrict__ ei, int* __restrict__ bcursor,
                      int2* __restrict__ edges) {
    __shared__ int lsrc[BIN_CHUNK];
    __shared__ int ldst[BIN_CHUNK];
    __shared__ int hist[NB_BUCK];
    __shared__ int hbase[NB_BUCK];
    __shared__ int lcur[NB_BUCK];
    int tid = threadIdx.x;
    if (tid < NB_BUCK) { hist[tid] = 0; lcur[tid] = 0; }
    __syncthreads();
    int e0 = blockIdx.x * BIN_CHUNK;
    int nE = min(e0 + BIN_CHUNK, N_EDGES) - e0;
    for (int i = tid; i < nE; i += 256) {
        int s = ei[e0 + i];
        int d = ei[N_EDGES + e0 + i];
        lsrc[i] = s;
        ldst[i] = d;
        atomicAdd(&hist[d >> BUCK_SHIFT], 1);
    }
    __syncthreads();
    if (tid < NB_BUCK) {
        int h = hist[tid];
        hbase[tid] = (h > 0) ? atomicAdd(&bcursor[tid], h) : 0;
    }
    __syncthreads();
    for (int i = tid; i < nE; i += 256) {
        int d = ldst[i];
        int b = d >> BUCK_SHIFT;
        int off = atomicAdd(&lcur[b], 1);
        edges[hbase[b] + off] = make_int2(lsrc[i], d);
    }
}

// ---------------- fill: per-bucket degree, rowp, dinv, CSR col ----------------

__global__ void k_fill(const int* __restrict__ bbase, const int2* __restrict__ edges,
                       int* __restrict__ rowp, float* __restrict__ dinv,
                       int* __restrict__ col) {
    __shared__ int ldeg[BUCK_SIZE];
    __shared__ int sa[BUCK_SIZE];
    __shared__ int sb[BUCK_SIZE];
    __shared__ int lcur[BUCK_SIZE];
    int b = blockIdx.x;
    int tid = threadIdx.x;
    int base_node = b << BUCK_SHIFT;
    int nn = min(BUCK_SIZE, N_NODES - base_node);
    int seg0 = bbase[b];
    int seg1 = bbase[b + 1];
    ldeg[tid] = 0;
    __syncthreads();
    for (int e = seg0 + tid; e < seg1; e += BUCK_SIZE) {
        atomicAdd(&ldeg[edges[e].y - base_node], 1);
    }
    __syncthreads();
    sa[tid] = ldeg[tid];
    __syncthreads();
    int* src = sa; int* dst = sb;
    for (int st = 1; st < BUCK_SIZE; st <<= 1) {
        int v = src[tid];
        if (tid >= st) v += src[tid - st];
        dst[tid] = v;
        __syncthreads();
        int* t = src; src = dst; dst = t;
    }
    int ex = (tid == 0) ? 0 : src[tid - 1];
    int rp = seg0 + ex;
    lcur[tid] = rp;
    if (tid < nn) {
        rowp[base_node + tid] = rp;
        dinv[base_node + tid] = rsqrtf((float)(ldeg[tid] + 1));
    }
    __syncthreads();
    for (int e = seg0 + tid; e < seg1; e += BUCK_SIZE) {
        int2 sd = edges[e];
        int p = atomicAdd(&lcur[sd.y - base_node], 1);
        col[p] = sd.x;
    }
}

// ---------------- cast X -> pre-scaled bf16 rows: Xb[n] = dinv[n]*X[n] ----------------

__global__ void k_castx(const float* __restrict__ X, const float* __restrict__ dinv,
                        unsigned* __restrict__ Xb) {
    int i = blockIdx.x * blockDim.x + threadIdx.x;
    if (i >= N_NODES * 32) return;
    int n = i >> 5, j = i & 31;
    float dv = dinv[n];
    float lo = 0.0f, hi = 0.0f;
    if (j < 17) {
        lo = X[(size_t)n * IN_CH + 2 * j];
        hi = X[(size_t)n * IN_CH + 2 * j + 1];
    } else if (j == 17) {
        lo = X[(size_t)n * IN_CH + 34];
    }
    Xb[i] = packbf2(dv * lo, dv * hi);
}

#define ACC8(v) { a0 += bflo(v.x); a1 += bfhi(v.x); a2 += bflo(v.y); a3 += bfhi(v.y); \
                  a4 += bflo(v.z); a5 += bfhi(v.z); a6 += bflo(v.w); a7 += bfhi(v.w); }
#define ACC4(v) { a0 += bflo(v.x); a1 += bfhi(v.x); a2 += bflo(v.y); a3 += bfhi(v.y); }

// ---------------- fused layer-1: Y1 = (A_norm X) W1 + b1 -> bf16 ----------------

#define C1_NODES 8

__global__ __launch_bounds__(512) void k_conv1(
        const unsigned* __restrict__ Xb, const int* __restrict__ rowp,
        const int* __restrict__ col, const float* __restrict__ dinv,
        const float* __restrict__ W1, const float* __restrict__ b1,
        unsigned* __restrict__ Yb) {
    __shared__ float w_s[IN_CH * HID];       // 17.9 KB
    __shared__ float b_s[HID];
    __shared__ float xa_s[C1_NODES][36];
    int tid = threadIdx.x;
    for (int u = tid; u < IN_CH * HID; u += 512) w_s[u] = W1[u];
    if (tid < HID) b_s[tid] = b1[tid];

    int wid = tid >> 6;
    int lane = tid & 63;
    int g = lane >> 4;
    int j = lane & 15;
    int node = blockIdx.x * C1_NODES + wid;
    bool valid = node < N_NODES;

    float a0 = 0.0f, a1 = 0.0f, a2 = 0.0f, a3 = 0.0f;
    float di = 0.0f;
    if (valid) {
        int rp0 = rowp[node], rp1 = rowp[node + 1];
        di = dinv[node];
        uint2 sv = *(const uint2*)(Xb + (size_t)node * 32 + j * 2);
        float w0 = (g == 0) ? 1.0f : 0.0f;
        a0 = w0 * bflo(sv.x); a1 = w0 * bfhi(sv.x);
        a2 = w0 * bflo(sv.y); a3 = w0 * bfhi(sv.y);
        unsigned deg = (unsigned)(rp1 - rp0);
        for (int e0 = (rp0 & ~3); e0 < rp1; e0 += 16) {
            int eb = e0 + 4 * g;
            int4 cs = *(const int4*)(col + eb);
            int s0 = ((unsigned)(eb + 0 - rp0) < deg) ? cs.x : N_NODES;
            int s1 = ((unsigned)(eb + 1 - rp0) < deg) ? cs.y : N_NODES;
            int s2 = ((unsigned)(eb + 2 - rp0) < deg) ? cs.z : N_NODES;
            int s3 = ((unsigned)(eb + 3 - rp0) < deg) ? cs.w : N_NODES;
            uint2 v0 = *(const uint2*)(Xb + (size_t)s0 * 32 + j * 2);
            uint2 v1 = *(const uint2*)(Xb + (size_t)s1 * 32 + j * 2);
            uint2 v2 = *(const uint2*)(Xb + (size_t)s2 * 32 + j * 2);
            uint2 v3 = *(const uint2*)(Xb + (size_t)s3 * 32 + j * 2);
            ACC4(v0); ACC4(v1); ACC4(v2); ACC4(v3);
        }
    }
    a0 += __shfl(a0, (lane + 32) & 63, 64);
    a1 += __shfl(a1, (lane + 32) & 63, 64);
    a2 += __shfl(a2, (lane + 32) & 63, 64);
    a3 += __shfl(a3, (lane + 32) & 63, 64);
    a0 += __shfl(a0, (lane + 16) & 63, 64);
    a1 += __shfl(a1, (lane + 16) & 63, 64);
    a2 += __shfl(a2, (lane + 16) & 63, 64);
    a3 += __shfl(a3, (lane + 16) & 63, 64);
    if (valid && g == 0 && j < 9) {
        xa_s[wid][4 * j + 0] = di * a0;
        xa_s[wid][4 * j + 1] = di * a1;
        xa_s[wid][4 * j + 2] = di * a2;
        xa_s[wid][4 * j + 3] = di * a3;
    }
    __syncthreads();
    float acc0 = b_s[2 * lane];
    float acc1 = b_s[2 * lane + 1];
    #pragma unroll 7
    for (int k = 0; k < IN_CH; ++k) {
        float xv = xa_s[wid][k];
        acc0 = fmaf(xv, w_s[k * HID + 2 * lane], acc0);
        acc1 = fmaf(xv, w_s[k * HID + 2 * lane + 1], acc1);
    }
    if (valid) Yb[(size_t)node * 64 + lane] = packbf2(acc0, acc1);
}

// ---------------- MFMA GEMM: Hb = dinv[row] * (gelu(BN(Yb)) @ W) -> bf16 ----------------
// 64 rows/block, 4 waves (each 16 rows x 128 cols). Activations staged as bf16
// in XOR-swizzled LDS; B-fragments read from pre-transposed bf16 Wt[n][k]
// (32 KB, L1-resident). v_mfma_f32_16x16x32_bf16, K=128 in 4 steps.

__global__ __launch_bounds__(256) void k_gemm128m(
        const unsigned* __restrict__ Yb, const float* __restrict__ stats,
        const float* __restrict__ g, const float* __restrict__ be,
        const unsigned* __restrict__ Wt, const float* __restrict__ dinv,
        unsigned* __restrict__ Hb) {
    __shared__ __align__(16) unsigned act[64 * 64];   // 16 KB
    __shared__ float sc_s[HID];
    __shared__ float sh_s[HID];
    int tid = threadIdx.x;
    if (tid < HID) {
        const float inv_n = 1.0f / (float)N_NODES;
        float mean = stats[tid] * inv_n;
        float var = stats[HID + tid] * inv_n - mean * mean;
        float s = g[tid] * rsqrtf(var + BN_EPS);
        sc_s[tid] = s;
        sh_s[tid] = be[tid] - mean * s;
    }
    __syncthreads();
    int row0 = blockIdx.x * 64;
    #pragma unroll
    for (int it = 0; it < 8; ++it) {
        int idx = it * 256 + tid;        // 0..2047
        int r = idx >> 5;                // block-local row 0..63
        int c2 = idx & 31;               // uint2 column index
        int gr = row0 + r;
        uint2 v = make_uint2(0u, 0u);
        if (gr < N_NODES) v = *(const uint2*)(Yb + (size_t)gr * 64 + c2 * 2);
        int c = c2 * 2;                  // channels 2c..2c+3
        float x0 = gelu_f(fmaf(bflo(v.x), sc_s[2 * c], sh_s[2 * c]));
        float x1 = gelu_f(fmaf(bfhi(v.x), sc_s[2 * c + 1], sh_s[2 * c + 1]));
        float x2 = gelu_f(fmaf(bflo(v.y), sc_s[2 * c + 2], sh_s[2 * c + 2]));
        float x3 = gelu_f(fmaf(bfhi(v.y), sc_s[2 * c + 3], sh_s[2 * c + 3]));
        int swz = (r & 7) << 2;
        act[r * 64 + (c ^ swz)]       = packbf2(x0, x1);
        act[r * 64 + ((c + 1) ^ swz)] = packbf2(x2, x3);
    }
    __syncthreads();
    int l = tid & 63;
    int w = tid >> 6;
    int r0 = w * 16;
    int arow = r0 + (l & 15);            // A row (block-local)
    int kgrp = l >> 4;                   // 0..3
    bf16x8 afrag[4];
    #pragma unroll
    for (int kk = 0; kk < 4; ++kk) {
        int base = (kk * 16 + kgrp * 4) ^ ((arow & 7) << 2);
        afrag[kk] = *(const bf16x8*)&act[arow * 64 + base];
    }
    float dv[4];
    #pragma unroll
    for (int reg = 0; reg < 4; ++reg) {
        int gr = row0 + r0 + kgrp * 4 + reg;
        dv[reg] = (gr < N_NODES) ? dinv[gr] : 0.0f;
    }
    unsigned short* Hb16 = (unsigned short*)Hb;
    #pragma unroll
    for (int n0 = 0; n0 < 8; ++n0) {
        f32x4 acc = {0.0f, 0.0f, 0.0f, 0.0f};
        #pragma unroll
        for (int kk = 0; kk < 4; ++kk) {
            bf16x8 b = *(const bf16x8*)&Wt[(n0 * 16 + (l & 15)) * 64 + kk * 16 + kgrp * 4];
            acc = __builtin_amdgcn_mfma_f32_16x16x32_bf16(afrag[kk], b, acc, 0, 0, 0);
        }
        int colg = n0 * 16 + (l & 15);
        #pragma unroll
        for (int reg = 0; reg < 4; ++reg) {
            int gr = row0 + r0 + kgrp * 4 + reg;
            if (gr < N_NODES)
                Hb16[(size_t)gr * HID + colg] = (unsigned short)f2bf(dv[reg] * acc[reg]);
        }
    }
}

// ---------------- conv (pre-scaled bf16 gather) ----------------

__global__ void k_convb(const unsigned* __restrict__ Hb, const int* __restrict__ rowp,
                        const int* __restrict__ col, const float* __restrict__ dinv,
                        const float* __restrict__ bias, unsigned* __restrict__ Yb) {
    int tid = threadIdx.x;
    int wid = tid >> 6;
    int lane = tid & 63;
    int g = lane >> 4;
    int j = lane & 15;
    int node = blockIdx.x * 4 + wid;
    if (node >= N_NODES) return;
    int rp0 = rowp[node], rp1 = rowp[node + 1];
    float di = dinv[node];
    uint4 sv = *(const uint4*)(Hb + (size_t)node * 64 + j * 4);
    float w0 = (g == 0) ? 1.0f : 0.0f;
    float a0 = w0 * bflo(sv.x), a1 = w0 * bfhi(sv.x);
    float a2 = w0 * bflo(sv.y), a3 = w0 * bfhi(sv.y);
    float a4 = w0 * bflo(sv.z), a5 = w0 * bfhi(sv.z);
    float a6 = w0 * bflo(sv.w), a7 = w0 * bfhi(sv.w);
    unsigned deg = (unsigned)(rp1 - rp0);
    for (int e0 = (rp0 & ~3); e0 < rp1; e0 += 16) {
        int eb = e0 + 4 * g;
        int4 cs = *(const int4*)(col + eb);
        int s0 = ((unsigned)(eb + 0 - rp0) < deg) ? cs.x : N_NODES;
        int s1 = ((unsigned)(eb + 1 - rp0) < deg) ? cs.y : N_NODES;
        int s2 = ((unsigned)(eb + 2 - rp0) < deg) ? cs.z : N_NODES;
        int s3 = ((unsigned)(eb + 3 - rp0) < deg) ? cs.w : N_NODES;
        uint4 v0 = *(const uint4*)(Hb + (size_t)s0 * 64 + j * 4);
        uint4 v1 = *(const uint4*)(Hb + (size_t)s1 * 64 + j * 4);
        uint4 v2 = *(const uint4*)(Hb + (size_t)s2 * 64 + j * 4);
        uint4 v3 = *(const uint4*)(Hb + (size_t)s3 * 64 + j * 4);
        ACC8(v0); ACC8(v1); ACC8(v2); ACC8(v3);
    }
    a0 += __shfl(a0, (lane + 32) & 63, 64);
    a1 += __shfl(a1, (lane + 32) & 63, 64);
    a2 += __shfl(a2, (lane + 32) & 63, 64);
    a3 += __shfl(a3, (lane + 32) & 63, 64);
    a4 += __shfl(a4, (lane + 32) & 63, 64);
    a5 += __shfl(a5, (lane + 32) & 63, 64);
    a6 += __shfl(a6, (lane + 32) & 63, 64);
    a7 += __shfl(a7, (lane + 32) & 63, 64);
    a0 += __shfl(a0, (lane + 16) & 63, 64);
    a1 += __shfl(a1, (lane + 16) & 63, 64);
    a2 += __shfl(a2, (lane + 16) & 63, 64);
    a3 += __shfl(a3, (lane + 16) & 63, 64);
    a4 += __shfl(a4, (lane + 16) & 63, 64);
    a5 += __shfl(a5, (lane + 16) & 63, 64);
    a6 += __shfl(a6, (lane + 16) & 63, 64);
    a7 += __shfl(a7, (lane + 16) & 63, 64);
    if (g == 0) {
        const float4* bp = (const float4*)(bias + 8 * j);
        float4 bA = bp[0], bB = bp[1];
        uint4 o;
        o.x = packbf2(fmaf(di, a0, bA.x), fmaf(di, a1, bA.y));
        o.y = packbf2(fmaf(di, a2, bA.z), fmaf(di, a3, bA.w));
        o.z = packbf2(fmaf(di, a4, bB.x), fmaf(di, a5, bB.y));
        o.w = packbf2(fmaf(di, a6, bB.z), fmaf(di, a7, bB.w));
        *(uint4*)(Yb + (size_t)node * 64 + j * 4) = o;
    }
}

// ---------------- BN stats over bf16 Y ----------------

__global__ void k_statsb(const unsigned* __restrict__ Yb, float* __restrict__ stats) {
    __shared__ float ls[128];
    __shared__ float lss[128];
    int tid = threadIdx.x;
    int lane = tid & 63, grp = tid >> 6;
    if (tid < 128) { ls[tid] = 0.0f; lss[tid] = 0.0f; }
    __syncthreads();
    float s0 = 0, s1 = 0, q0 = 0, q1 = 0;
    for (int r = blockIdx.x * 4 + grp; r < N_NODES; r += gridDim.x * 4) {
        unsigned v = Yb[(size_t)r * 64 + lane];
        float lo = bflo(v), hi = bfhi(v);
        s0 += lo; q0 = fmaf(lo, lo, q0);
        s1 += hi; q1 = fmaf(hi, hi, q1);
    }
    atomicAdd(&ls[2 * lane], s0);
    atomicAdd(&ls[2 * lane + 1], s1);
    atomicAdd(&lss[2 * lane], q0);
    atomicAdd(&lss[2 * lane + 1], q1);
    __syncthreads();
    if (tid < 128) {
        atomicAdd(&stats[tid], ls[tid]);
        atomicAdd(&stats[128 + tid], lss[tid]);
    }
}

// ---------------- fused pool + MLP head ----------------

__device__ __forceinline__ int lowerb(const int* __restrict__ arr, int n, int key) {
    int lo = 0, hi = n;
    while (lo < hi) {
        int mid = (lo + hi) >> 1;
        if (arr[mid] < key) lo = mid + 1; else hi = mid;
    }
    return lo;
}

__global__ void k_pool_mlp(const unsigned* __restrict__ Yb, const float* __restrict__ stats,
                           const float* __restrict__ g, const float* __restrict__ be,
                           const int* __restrict__ batch,
                           const float* __restrict__ Wl1, const float* __restrict__ bl1,
                           const float* __restrict__ Wl2, const float* __restrict__ bl2,
                           float* __restrict__ out) {
    __shared__ float pooled[128];
    __shared__ float sc_s[128];
    __shared__ float sh_s[128];
    __shared__ int bounds[2];
    int gidx = blockIdx.x;
    int tid = threadIdx.x;
    if (tid < 128) {
        const float inv_n = 1.0f / (float)N_NODES;
        float mean = stats[tid] * inv_n;
        float var = stats[128 + tid] * inv_n - mean * mean;
        float s = g[tid] * rsqrtf(var + BN_EPS);
        sc_s[tid] = s;
        sh_s[tid] = be[tid] - mean * s;
    }
    if (tid == 0) {
        bounds[0] = lowerb(batch, N_NODES, gidx);
        bounds[1] = lowerb(batch, N_NODES, gidx + 1);
    }
    __syncthreads();
    int lo = bounds[0], hi = bounds[1];
    float s = sc_s[tid], h = sh_s[tid];
    int half = tid & 1;
    int word = tid >> 1;
    float acc = 0.0f;
    for (int r = lo; r < hi; ++r) {
        unsigned v = Yb[(size_t)r * 64 + word];
        float x = half ? bfhi(v) : bflo(v);
        acc += gelu_f(fmaf(x, s, h));
    }
    pooled[tid] = (hi > lo) ? acc / (float)(hi - lo) : 0.0f;
    __syncthreads();
    if (tid < 64) {
        float hs = bl1[tid];
        #pragma unroll 4
        for (int k = 0; k < 128; ++k)
            hs = fmaf(pooled[k], Wl1[k * 64 + tid], hs);
        float e = (hs > 0.0f) ? hs : expm1f(hs);
        float part = e * Wl2[tid];
        #pragma unroll
        for (int o = 32; o > 0; o >>= 1)
            part += __shfl_down(part, o);
        if (tid == 0) out[gidx] = part + bl2[0];
    }
}

// ---------------- host launch ----------------

extern "C" void kernel_launch(void* const* d_in, const int* in_sizes, int n_in,
                              void* d_out, int out_size, void* d_ws, size_t ws_size,
                              hipStream_t stream) {
    const float* x   = (const float*)d_in[0];
    const int*   ei  = (const int*)d_in[1];
    const int*   bat = (const int*)d_in[2];
    const float* W1  = (const float*)d_in[3];
    const float* b1  = (const float*)d_in[4];
    const float* g1  = (const float*)d_in[5];
    const float* be1 = (const float*)d_in[6];
    const float* W2  = (const float*)d_in[7];
    const float* b2  = (const float*)d_in[8];
    const float* g2  = (const float*)d_in[9];
    const float* be2 = (const float*)d_in[10];
    const float* W3  = (const float*)d_in[11];
    const float* b3  = (const float*)d_in[12];
    const float* g3  = (const float*)d_in[13];
    const float* be3 = (const float*)d_in[14];
    const float* Wl1 = (const float*)d_in[15];
    const float* bl1 = (const float*)d_in[16];
    const float* Wl2 = (const float*)d_in[17];
    const float* bl2 = (const float*)d_in[18];
    float* out = (float*)d_out;

    char* ws = (char*)d_ws;
    size_t off = 0;
    auto alloc = [&](size_t bytes) -> char* {
        char* p = ws + off;
        off += (bytes + 255) & ~(size_t)255;
        return p;
    };
    int*      bcnt    = (int*)alloc(NB_BUCK * sizeof(int));
    int*      bbase   = (int*)alloc((NB_BUCK + 1) * sizeof(int));
    int*      bcursor = (int*)alloc(NB_BUCK * sizeof(int));
    int2*     edges   = (int2*)alloc((size_t)N_EDGES * sizeof(int2));
    int*      rowp    = (int*)alloc((N_NODES + 1) * sizeof(int));
    float*    dinv    = (float*)alloc(N_NODES * sizeof(float));
    int*      col     = (int*)alloc((size_t)N_EDGES * sizeof(int));
    unsigned* Xb      = (unsigned*)alloc((size_t)(N_NODES + 1) * 32 * sizeof(unsigned));
    unsigned* Ybuf    = (unsigned*)alloc((size_t)N_NODES * 64 * sizeof(unsigned));
    unsigned* Hbuf    = (unsigned*)alloc((size_t)(N_NODES + 1) * 64 * sizeof(unsigned));
    float*    stats   = (float*)alloc(3 * 256 * sizeof(float));
    unsigned* Wt2     = (unsigned*)alloc(8192 * sizeof(unsigned));
    unsigned* Wt3     = (unsigned*)alloc(8192 * sizeof(unsigned));

    // ---- graph structure + casts ----
    k_zero2<<<1, 1024, 0, stream>>>(bcnt, stats, Xb + (size_t)N_NODES * 32,
                                    Hbuf + (size_t)N_NODES * 64);
    k_wcast<<<64, 256, 0, stream>>>(W2, W3, Wt2, Wt3);
    k_bhist<<<BIN_GRID, 256, 0, stream>>>(ei, bcnt);
    k_bscan<<<1, 256, 0, stream>>>(bcnt, bbase, bcursor, rowp);
    k_bin<<<BIN_GRID, 256, 0, stream>>>(ei, bcursor, edges);
    k_fill<<<NB_BUCK, BUCK_SIZE, 0, stream>>>(bbase, edges, rowp, dinv, col);
    k_castx<<<(N_NODES * 32 + 255) / 256, 256, 0, stream>>>(x, dinv, Xb);

    const int gemm_blocks = (N_NODES + 63) / 64;
    const int conv_blocks = (N_NODES + 3) / 4;

    // ---- layer 1 (fused aggregate + GEMM) ----
    k_conv1<<<(N_NODES + C1_NODES - 1) / C1_NODES, 512, 0, stream>>>(
        Xb, rowp, col, dinv, W1, b1, Ybuf);
    k_statsb<<<1024, 256, 0, stream>>>(Ybuf, stats + 0 * 256);

    // ---- layer 2 ----
    k_gemm128m<<<gemm_blocks, 256, 0, stream>>>(Ybuf, stats + 0 * 256, g1, be1, Wt2, dinv, Hbuf);
    k_convb<<<conv_blocks, 256, 0, stream>>>(Hbuf, rowp, col, dinv, b2, Ybuf);
    k_statsb<<<1024, 256, 0, stream>>>(Ybuf, stats + 1 * 256);

    // ---- layer 3 ----
    k_gemm128m<<<gemm_blocks, 256, 0, stream>>>(Ybuf, stats + 1 * 256, g2, be2, Wt3, dinv, Hbuf);
    k_convb<<<conv_blocks, 256, 0, stream>>>(Hbuf, rowp, col, dinv, b3, Ybuf);
    k_statsb<<<1024, 256, 0, stream>>>(Ybuf, stats + 2 * 256);

    // ---- pool + head ----
    k_pool_mlp<<<NUM_GRAPHS, 128, 0, stream>>>(Ybuf, stats + 2 * 256, g3, be3, bat,
                                               Wl1, bl1, Wl2, bl2, out);
}

// Round 9
// 677.457 us; speedup vs baseline: 2.5950x; 1.0931x over previous
//
#include <hip/hip_runtime.h>
#include <hip/hip_bf16.h>
#include <math.h>

#define N_NODES 100000
#define N_EDGES 3200000
#define NUM_GRAPHS 2048
#define IN_CH 35
#define HID 128
#define BN_EPS 1e-5f

#define BUCK_SHIFT 9
#define BUCK_SIZE 512
#define NB_BUCK 196          // ceil(100000/512)
#define BUCK_CAP 18432       // mean 16327 + ~16 sigma, multiple of 4
#define BIN_GRID 1024
#define BIN_CHUNK 3128       // multiple of 4; 1024*3128 >= 3.2M; tail = 56

typedef short bf16x8 __attribute__((ext_vector_type(8)));
typedef float f32x4 __attribute__((ext_vector_type(4)));

__device__ __forceinline__ float gelu_f(float x) {
    return 0.5f * x * (1.0f + erff(x * 0.70710678118654752440f));
}

// bf16 helpers: packed 2 x bf16 in a uint (lo = even channel, hi = odd channel)
__device__ __forceinline__ float bflo(unsigned v) { return __uint_as_float(v << 16); }
__device__ __forceinline__ float bfhi(unsigned v) { return __uint_as_float(v & 0xffff0000u); }
__device__ __forceinline__ unsigned f2bf(float f) {
    unsigned x = __float_as_uint(f);
    return (x + 0x7fffu + ((x >> 16) & 1u)) >> 16;   // RNE
}
__device__ __forceinline__ unsigned packbf2(float lo, float hi) {
    return f2bf(lo) | (f2bf(hi) << 16);
}

// ---------------- zero bucket counters + stats + pad rows ----------------

__global__ void k_zero2(int* __restrict__ gcnt, float* __restrict__ stats,
                        unsigned* __restrict__ xzero, unsigned* __restrict__ hzero) {
    int i = threadIdx.x;
    if (i < NB_BUCK) gcnt[i] = 0;
    if (i < 3 * 256) stats[i] = 0.0f;
    if (i < 32) xzero[i] = 0u;   // Xb pad row (node N_NODES)
    if (i < 64) hzero[i] = 0u;   // Hb pad row (node N_NODES)
}

// ---------------- W2/W3 -> bf16 transposed Wt[n][k] (packed pairs along k) ----------------

__global__ void k_wcast(const float* __restrict__ W2, const float* __restrict__ W3,
                        unsigned* __restrict__ Wt2, unsigned* __restrict__ Wt3) {
    int t = blockIdx.x * 256 + threadIdx.x;
    if (t >= 2 * 8192) return;
    const float* W = (t < 8192) ? W2 : W3;
    unsigned* Wt = (t < 8192) ? Wt2 : Wt3;
    int i = t & 8191;
    int n = i >> 6, j = i & 63;
    Wt[n * 64 + j] = packbf2(W[(2 * j) * HID + n], W[(2 * j + 1) * HID + n]);
}

// ---------------- bin: one pass, fixed-capacity buckets, packed edges ----------------
// edge word: src (bits 0..16) | (dst & 511) (bits 17..25)

__global__ void k_bin(const int* __restrict__ ei, int* __restrict__ gcnt,
                      unsigned* __restrict__ epack) {
    __shared__ unsigned lpack[BIN_CHUNK];
    __shared__ unsigned char lbuck[BIN_CHUNK];
    __shared__ int hist[NB_BUCK];
    __shared__ int hbase[NB_BUCK];
    __shared__ int lcur[NB_BUCK];
    int tid = threadIdx.x;
    if (tid < NB_BUCK) { hist[tid] = 0; lcur[tid] = 0; }
    __syncthreads();
    int e0 = blockIdx.x * BIN_CHUNK;
    int nE = min(e0 + BIN_CHUNK, N_EDGES) - e0;   // always multiple of 4
    for (int i = tid * 4; i < nE; i += 1024) {
        int4 s4 = *(const int4*)(ei + e0 + i);
        int4 d4 = *(const int4*)(ei + N_EDGES + e0 + i);
        lpack[i + 0] = (unsigned)s4.x | (((unsigned)d4.x & 511u) << 17);
        lpack[i + 1] = (unsigned)s4.y | (((unsigned)d4.y & 511u) << 17);
        lpack[i + 2] = (unsigned)s4.z | (((unsigned)d4.z & 511u) << 17);
        lpack[i + 3] = (unsigned)s4.w | (((unsigned)d4.w & 511u) << 17);
        int b0 = d4.x >> BUCK_SHIFT, b1 = d4.y >> BUCK_SHIFT;
        int b2 = d4.z >> BUCK_SHIFT, b3 = d4.w >> BUCK_SHIFT;
        lbuck[i + 0] = (unsigned char)b0;
        lbuck[i + 1] = (unsigned char)b1;
        lbuck[i + 2] = (unsigned char)b2;
        lbuck[i + 3] = (unsigned char)b3;
        atomicAdd(&hist[b0], 1);
        atomicAdd(&hist[b1], 1);
        atomicAdd(&hist[b2], 1);
        atomicAdd(&hist[b3], 1);
    }
    __syncthreads();
    if (tid < NB_BUCK) {
        int h = hist[tid];
        hbase[tid] = (h > 0) ? (tid * BUCK_CAP + atomicAdd(&gcnt[tid], h)) : 0;
    }
    __syncthreads();
    for (int i = tid; i < nE; i += 256) {
        int b = lbuck[i];
        int off = atomicAdd(&lcur[b], 1);
        epack[hbase[b] + off] = lpack[i];
    }
}

// ---------------- fill: per-bucket degree, rowp/rowpEnd, dinv, CSR col ----------------

__global__ void k_fill(const int* __restrict__ gcnt, const unsigned* __restrict__ epack,
                       int* __restrict__ rowp, int* __restrict__ rowpEnd,
                       float* __restrict__ dinv, int* __restrict__ col) {
    __shared__ int ldeg[BUCK_SIZE];
    __shared__ int sa[BUCK_SIZE];
    __shared__ int sb[BUCK_SIZE];
    __shared__ int lcur[BUCK_SIZE];
    int b = blockIdx.x;
    int tid = threadIdx.x;
    int base_node = b << BUCK_SHIFT;
    int nn = min(BUCK_SIZE, N_NODES - base_node);
    int seg0 = b * BUCK_CAP;
    int seg1 = seg0 + gcnt[b];
    ldeg[tid] = 0;
    __syncthreads();
    for (int e = seg0 + tid; e < seg1; e += BUCK_SIZE) {
        atomicAdd(&ldeg[epack[e] >> 17], 1);
    }
    __syncthreads();
    sa[tid] = ldeg[tid];
    __syncthreads();
    int* src = sa; int* dst = sb;
    for (int st = 1; st < BUCK_SIZE; st <<= 1) {
        int v = src[tid];
        if (tid >= st) v += src[tid - st];
        dst[tid] = v;
        __syncthreads();
        int* t = src; src = dst; dst = t;
    }
    int ex = (tid == 0) ? 0 : src[tid - 1];
    int rp = seg0 + ex;
    lcur[tid] = rp;
    if (tid < nn) {
        rowp[base_node + tid] = rp;
        rowpEnd[base_node + tid] = rp + ldeg[tid];
        dinv[base_node + tid] = rsqrtf((float)(ldeg[tid] + 1));
    }
    __syncthreads();
    for (int e = seg0 + tid; e < seg1; e += BUCK_SIZE) {
        unsigned v = epack[e];
        int p = atomicAdd(&lcur[v >> 17], 1);
        col[p] = (int)(v & 0x1FFFFu);
    }
}

// ---------------- cast X -> pre-scaled bf16 rows: Xb[n] = dinv[n]*X[n] ----------------

__global__ void k_castx(const float* __restrict__ X, const float* __restrict__ dinv,
                        unsigned* __restrict__ Xb) {
    int i = blockIdx.x * blockDim.x + threadIdx.x;
    if (i >= N_NODES * 32) return;
    int n = i >> 5, j = i & 31;
    float dv = dinv[n];
    float lo = 0.0f, hi = 0.0f;
    if (j < 17) {
        lo = X[(size_t)n * IN_CH + 2 * j];
        hi = X[(size_t)n * IN_CH + 2 * j + 1];
    } else if (j == 17) {
        lo = X[(size_t)n * IN_CH + 34];
    }
    Xb[i] = packbf2(dv * lo, dv * hi);
}

#define ACC8(v) { a0 += bflo(v.x); a1 += bfhi(v.x); a2 += bflo(v.y); a3 += bfhi(v.y); \
                  a4 += bflo(v.z); a5 += bfhi(v.z); a6 += bflo(v.w); a7 += bfhi(v.w); }
#define ACC4(v) { a0 += bflo(v.x); a1 += bfhi(v.x); a2 += bflo(v.y); a3 += bfhi(v.y); }

// ---------------- fused layer-1: Y1 = (A_norm X) W1 + b1 -> bf16 ----------------
// 32 edges in flight per wave: 4 groups x 16 lanes, group g owns 4-edge runs at
// e0+4g and e0+16+4g (2 int4 index loads, 8 uint2 row loads per iteration).

#define C1_NODES 8

__global__ __launch_bounds__(512) void k_conv1(
        const unsigned* __restrict__ Xb, const int* __restrict__ rowp,
        const int* __restrict__ rowpEnd, const int* __restrict__ col,
        const float* __restrict__ dinv,
        const float* __restrict__ W1, const float* __restrict__ b1,
        unsigned* __restrict__ Yb) {
    __shared__ float w_s[IN_CH * HID];       // 17.9 KB
    __shared__ float b_s[HID];
    __shared__ float xa_s[C1_NODES][36];
    int tid = threadIdx.x;
    for (int u = tid; u < IN_CH * HID; u += 512) w_s[u] = W1[u];
    if (tid < HID) b_s[tid] = b1[tid];

    int wid = tid >> 6;
    int lane = tid & 63;
    int g = lane >> 4;
    int j = lane & 15;
    int node = blockIdx.x * C1_NODES + wid;
    bool valid = node < N_NODES;

    float a0 = 0.0f, a1 = 0.0f, a2 = 0.0f, a3 = 0.0f;
    float di = 0.0f;
    if (valid) {
        int rp0 = rowp[node], rp1 = rowpEnd[node];
        di = dinv[node];
        uint2 sv = *(const uint2*)(Xb + (size_t)node * 32 + j * 2);
        float w0 = (g == 0) ? 1.0f : 0.0f;
        a0 = w0 * bflo(sv.x); a1 = w0 * bfhi(sv.x);
        a2 = w0 * bflo(sv.y); a3 = w0 * bfhi(sv.y);
        unsigned deg = (unsigned)(rp1 - rp0);
        for (int e0 = (rp0 & ~3); e0 < rp1; e0 += 32) {
            int ebA = e0 + 4 * g;
            int ebB = ebA + 16;
            int4 cA = *(const int4*)(col + ebA);
            int4 cB = *(const int4*)(col + ebB);
            int s0 = ((unsigned)(ebA + 0 - rp0) < deg) ? cA.x : N_NODES;
            int s1 = ((unsigned)(ebA + 1 - rp0) < deg) ? cA.y : N_NODES;
            int s2 = ((unsigned)(ebA + 2 - rp0) < deg) ? cA.z : N_NODES;
            int s3 = ((unsigned)(ebA + 3 - rp0) < deg) ? cA.w : N_NODES;
            int s4 = ((unsigned)(ebB + 0 - rp0) < deg) ? cB.x : N_NODES;
            int s5 = ((unsigned)(ebB + 1 - rp0) < deg) ? cB.y : N_NODES;
            int s6 = ((unsigned)(ebB + 2 - rp0) < deg) ? cB.z : N_NODES;
            int s7 = ((unsigned)(ebB + 3 - rp0) < deg) ? cB.w : N_NODES;
            uint2 v0 = *(const uint2*)(Xb + (size_t)s0 * 32 + j * 2);
            uint2 v1 = *(const uint2*)(Xb + (size_t)s1 * 32 + j * 2);
            uint2 v2 = *(const uint2*)(Xb + (size_t)s2 * 32 + j * 2);
            uint2 v3 = *(const uint2*)(Xb + (size_t)s3 * 32 + j * 2);
            uint2 v4 = *(const uint2*)(Xb + (size_t)s4 * 32 + j * 2);
            uint2 v5 = *(const uint2*)(Xb + (size_t)s5 * 32 + j * 2);
            uint2 v6 = *(const uint2*)(Xb + (size_t)s6 * 32 + j * 2);
            uint2 v7 = *(const uint2*)(Xb + (size_t)s7 * 32 + j * 2);
            ACC4(v0); ACC4(v1); ACC4(v2); ACC4(v3);
            ACC4(v4); ACC4(v5); ACC4(v6); ACC4(v7);
        }
    }
    a0 += __shfl(a0, (lane + 32) & 63, 64);
    a1 += __shfl(a1, (lane + 32) & 63, 64);
    a2 += __shfl(a2, (lane + 32) & 63, 64);
    a3 += __shfl(a3, (lane + 32) & 63, 64);
    a0 += __shfl(a0, (lane + 16) & 63, 64);
    a1 += __shfl(a1, (lane + 16) & 63, 64);
    a2 += __shfl(a2, (lane + 16) & 63, 64);
    a3 += __shfl(a3, (lane + 16) & 63, 64);
    if (valid && g == 0 && j < 9) {
        xa_s[wid][4 * j + 0] = di * a0;
        xa_s[wid][4 * j + 1] = di * a1;
        xa_s[wid][4 * j + 2] = di * a2;
        xa_s[wid][4 * j + 3] = di * a3;
    }
    __syncthreads();
    float acc0 = b_s[2 * lane];
    float acc1 = b_s[2 * lane + 1];
    #pragma unroll 7
    for (int k = 0; k < IN_CH; ++k) {
        float xv = xa_s[wid][k];
        acc0 = fmaf(xv, w_s[k * HID + 2 * lane], acc0);
        acc1 = fmaf(xv, w_s[k * HID + 2 * lane + 1], acc1);
    }
    if (valid) Yb[(size_t)node * 64 + lane] = packbf2(acc0, acc1);
}

// ---------------- MFMA GEMM: Hb = dinv[row] * (gelu(BN(Yb)) @ W) -> bf16 ----------------

__global__ __launch_bounds__(256) void k_gemm128m(
        const unsigned* __restrict__ Yb, const float* __restrict__ stats,
        const float* __restrict__ g, const float* __restrict__ be,
        const unsigned* __restrict__ Wt, const float* __restrict__ dinv,
        unsigned* __restrict__ Hb) {
    __shared__ __align__(16) unsigned act[64 * 64];   // 16 KB
    __shared__ float sc_s[HID];
    __shared__ float sh_s[HID];
    int tid = threadIdx.x;
    if (tid < HID) {
        const float inv_n = 1.0f / (float)N_NODES;
        float mean = stats[tid] * inv_n;
        float var = stats[HID + tid] * inv_n - mean * mean;
        float s = g[tid] * rsqrtf(var + BN_EPS);
        sc_s[tid] = s;
        sh_s[tid] = be[tid] - mean * s;
    }
    __syncthreads();
    int row0 = blockIdx.x * 64;
    #pragma unroll
    for (int it = 0; it < 8; ++it) {
        int idx = it * 256 + tid;        // 0..2047
        int r = idx >> 5;                // block-local row 0..63
        int c2 = idx & 31;               // uint2 column index
        int gr = row0 + r;
        uint2 v = make_uint2(0u, 0u);
        if (gr < N_NODES) v = *(const uint2*)(Yb + (size_t)gr * 64 + c2 * 2);
        int c = c2 * 2;                  // uint columns c, c+1
        float x0 = gelu_f(fmaf(bflo(v.x), sc_s[2 * c], sh_s[2 * c]));
        float x1 = gelu_f(fmaf(bfhi(v.x), sc_s[2 * c + 1], sh_s[2 * c + 1]));
        float x2 = gelu_f(fmaf(bflo(v.y), sc_s[2 * c + 2], sh_s[2 * c + 2]));
        float x3 = gelu_f(fmaf(bfhi(v.y), sc_s[2 * c + 3], sh_s[2 * c + 3]));
        int swz = (r & 7) << 2;
        act[r * 64 + (c ^ swz)]       = packbf2(x0, x1);
        act[r * 64 + ((c + 1) ^ swz)] = packbf2(x2, x3);
    }
    __syncthreads();
    int l = tid & 63;
    int w = tid >> 6;
    int r0 = w * 16;
    int arow = r0 + (l & 15);            // A row (block-local)
    int kgrp = l >> 4;                   // 0..3
    bf16x8 afrag[4];
    #pragma unroll
    for (int kk = 0; kk < 4; ++kk) {
        int base = (kk * 16 + kgrp * 4) ^ ((arow & 7) << 2);
        afrag[kk] = *(const bf16x8*)&act[arow * 64 + base];
    }
    float dv[4];
    #pragma unroll
    for (int reg = 0; reg < 4; ++reg) {
        int gr = row0 + r0 + kgrp * 4 + reg;
        dv[reg] = (gr < N_NODES) ? dinv[gr] : 0.0f;
    }
    unsigned short* Hb16 = (unsigned short*)Hb;
    #pragma unroll
    for (int n0 = 0; n0 < 8; ++n0) {
        f32x4 acc = {0.0f, 0.0f, 0.0f, 0.0f};
        #pragma unroll
        for (int kk = 0; kk < 4; ++kk) {
            bf16x8 b = *(const bf16x8*)&Wt[(n0 * 16 + (l & 15)) * 64 + kk * 16 + kgrp * 4];
            acc = __builtin_amdgcn_mfma_f32_16x16x32_bf16(afrag[kk], b, acc, 0, 0, 0);
        }
        int colg = n0 * 16 + (l & 15);
        #pragma unroll
        for (int reg = 0; reg < 4; ++reg) {
            int gr = row0 + r0 + kgrp * 4 + reg;
            if (gr < N_NODES)
                Hb16[(size_t)gr * HID + colg] = (unsigned short)f2bf(dv[reg] * acc[reg]);
        }
    }
}

// ---------------- conv (pre-scaled bf16 gather): 32 edges in flight ----------------

__global__ void k_convb(const unsigned* __restrict__ Hb, const int* __restrict__ rowp,
                        const int* __restrict__ rowpEnd, const int* __restrict__ col,
                        const float* __restrict__ dinv,
                        const float* __restrict__ bias, unsigned* __restrict__ Yb) {
    int tid = threadIdx.x;
    int wid = tid >> 6;
    int lane = tid & 63;
    int g = lane >> 4;
    int j = lane & 15;
    int node = blockIdx.x * 4 + wid;
    if (node >= N_NODES) return;
    int rp0 = rowp[node], rp1 = rowpEnd[node];
    float di = dinv[node];
    uint4 sv = *(const uint4*)(Hb + (size_t)node * 64 + j * 4);
    float w0 = (g == 0) ? 1.0f : 0.0f;
    float a0 = w0 * bflo(sv.x), a1 = w0 * bfhi(sv.x);
    float a2 = w0 * bflo(sv.y), a3 = w0 * bfhi(sv.y);
    float a4 = w0 * bflo(sv.z), a5 = w0 * bfhi(sv.z);
    float a6 = w0 * bflo(sv.w), a7 = w0 * bfhi(sv.w);
    unsigned deg = (unsigned)(rp1 - rp0);
    for (int e0 = (rp0 & ~3); e0 < rp1; e0 += 32) {
        int ebA = e0 + 4 * g;
        int ebB = ebA + 16;
        int4 cA = *(const int4*)(col + ebA);
        int4 cB = *(const int4*)(col + ebB);
        int s0 = ((unsigned)(ebA + 0 - rp0) < deg) ? cA.x : N_NODES;
        int s1 = ((unsigned)(ebA + 1 - rp0) < deg) ? cA.y : N_NODES;
        int s2 = ((unsigned)(ebA + 2 - rp0) < deg) ? cA.z : N_NODES;
        int s3 = ((unsigned)(ebA + 3 - rp0) < deg) ? cA.w : N_NODES;
        int s4 = ((unsigned)(ebB + 0 - rp0) < deg) ? cB.x : N_NODES;
        int s5 = ((unsigned)(ebB + 1 - rp0) < deg) ? cB.y : N_NODES;
        int s6 = ((unsigned)(ebB + 2 - rp0) < deg) ? cB.z : N_NODES;
        int s7 = ((unsigned)(ebB + 3 - rp0) < deg) ? cB.w : N_NODES;
        uint4 v0 = *(const uint4*)(Hb + (size_t)s0 * 64 + j * 4);
        uint4 v1 = *(const uint4*)(Hb + (size_t)s1 * 64 + j * 4);
        uint4 v2 = *(const uint4*)(Hb + (size_t)s2 * 64 + j * 4);
        uint4 v3 = *(const uint4*)(Hb + (size_t)s3 * 64 + j * 4);
        uint4 v4 = *(const uint4*)(Hb + (size_t)s4 * 64 + j * 4);
        uint4 v5 = *(const uint4*)(Hb + (size_t)s5 * 64 + j * 4);
        uint4 v6 = *(const uint4*)(Hb + (size_t)s6 * 64 + j * 4);
        uint4 v7 = *(const uint4*)(Hb + (size_t)s7 * 64 + j * 4);
        ACC8(v0); ACC8(v1); ACC8(v2); ACC8(v3);
        ACC8(v4); ACC8(v5); ACC8(v6); ACC8(v7);
    }
    a0 += __shfl(a0, (lane + 32) & 63, 64);
    a1 += __shfl(a1, (lane + 32) & 63, 64);
    a2 += __shfl(a2, (lane + 32) & 63, 64);
    a3 += __shfl(a3, (lane + 32) & 63, 64);
    a4 += __shfl(a4, (lane + 32) & 63, 64);
    a5 += __shfl(a5, (lane + 32) & 63, 64);
    a6 += __shfl(a6, (lane + 32) & 63, 64);
    a7 += __shfl(a7, (lane + 32) & 63, 64);
    a0 += __shfl(a0, (lane + 16) & 63, 64);
    a1 += __shfl(a1, (lane + 16) & 63, 64);
    a2 += __shfl(a2, (lane + 16) & 63, 64);
    a3 += __shfl(a3, (lane + 16) & 63, 64);
    a4 += __shfl(a4, (lane + 16) & 63, 64);
    a5 += __shfl(a5, (lane + 16) & 63, 64);
    a6 += __shfl(a6, (lane + 16) & 63, 64);
    a7 += __shfl(a7, (lane + 16) & 63, 64);
    if (g == 0) {
        const float4* bp = (const float4*)(bias + 8 * j);
        float4 bA = bp[0], bB = bp[1];
        uint4 o;
        o.x = packbf2(fmaf(di, a0, bA.x), fmaf(di, a1, bA.y));
        o.y = packbf2(fmaf(di, a2, bA.z), fmaf(di, a3, bA.w));
        o.z = packbf2(fmaf(di, a4, bB.x), fmaf(di, a5, bB.y));
        o.w = packbf2(fmaf(di, a6, bB.z), fmaf(di, a7, bB.w));
        *(uint4*)(Yb + (size_t)node * 64 + j * 4) = o;
    }
}

// ---------------- BN stats over bf16 Y (uint4 loads, 16 lanes/row) ----------------

__global__ void k_statsb(const unsigned* __restrict__ Yb, float* __restrict__ stats) {
    __shared__ float red[16][128];
    __shared__ float red2[16][128];
    int tid = threadIdx.x;
    int j = tid & 15;            // uint4 index: channels 8j..8j+7
    int rg = tid >> 4;           // 0..15
    float s[8] = {0, 0, 0, 0, 0, 0, 0, 0};
    float q[8] = {0, 0, 0, 0, 0, 0, 0, 0};
    for (int r = blockIdx.x * 16 + rg; r < N_NODES; r += gridDim.x * 16) {
        uint4 v = *(const uint4*)(Yb + (size_t)r * 64 + j * 4);
        float x;
        x = bflo(v.x); s[0] += x; q[0] = fmaf(x, x, q[0]);
        x = bfhi(v.x); s[1] += x; q[1] = fmaf(x, x, q[1]);
        x = bflo(v.y); s[2] += x; q[2] = fmaf(x, x, q[2]);
        x = bfhi(v.y); s[3] += x; q[3] = fmaf(x, x, q[3]);
        x = bflo(v.z); s[4] += x; q[4] = fmaf(x, x, q[4]);
        x = bfhi(v.z); s[5] += x; q[5] = fmaf(x, x, q[5]);
        x = bflo(v.w); s[6] += x; q[6] = fmaf(x, x, q[6]);
        x = bfhi(v.w); s[7] += x; q[7] = fmaf(x, x, q[7]);
    }
    #pragma unroll
    for (int k = 0; k < 8; ++k) {
        red[rg][8 * j + k]  = s[k];
        red2[rg][8 * j + k] = q[k];
    }
    __syncthreads();
    if (tid < 128) {
        float S = 0.0f, Q = 0.0f;
        #pragma unroll
        for (int r = 0; r < 16; ++r) { S += red[r][tid]; Q += red2[r][tid]; }
        atomicAdd(&stats[tid], S);
        atomicAdd(&stats[128 + tid], Q);
    }
}

// ---------------- fused pool + MLP head (single-read) ----------------

__device__ __forceinline__ int lowerb(const int* __restrict__ arr, int n, int key) {
    int lo = 0, hi = n;
    while (lo < hi) {
        int mid = (lo + hi) >> 1;
        if (arr[mid] < key) lo = mid + 1; else hi = mid;
    }
    return lo;
}

__global__ void k_pool_mlp(const unsigned* __restrict__ Yb, const float* __restrict__ stats,
                           const float* __restrict__ g, const float* __restrict__ be,
                           const int* __restrict__ batch,
                           const float* __restrict__ Wl1, const float* __restrict__ bl1,
                           const float* __restrict__ Wl2, const float* __restrict__ bl2,
                           float* __restrict__ out) {
    __shared__ float pooled[128];
    __shared__ float part[2][128];
    __shared__ float sc_s[128];
    __shared__ float sh_s[128];
    __shared__ int bounds[2];
    int gidx = blockIdx.x;
    int tid = threadIdx.x;
    if (tid < 128) {
        const float inv_n = 1.0f / (float)N_NODES;
        float mean = stats[tid] * inv_n;
        float var = stats[128 + tid] * inv_n - mean * mean;
        float s = g[tid] * rsqrtf(var + BN_EPS);
        sc_s[tid] = s;
        sh_s[tid] = be[tid] - mean * s;
    }
    if (tid == 0) {
        bounds[0] = lowerb(batch, N_NODES, gidx);
        bounds[1] = lowerb(batch, N_NODES, gidx + 1);
    }
    __syncthreads();
    int lo = bounds[0], hi = bounds[1];
    int rofs = tid >> 6;         // 0 or 1
    int w = tid & 63;            // word index
    float sA = sc_s[2 * w], hA = sh_s[2 * w];
    float sB = sc_s[2 * w + 1], hB = sh_s[2 * w + 1];
    float accA = 0.0f, accB = 0.0f;
    for (int r = lo + rofs; r < hi; r += 2) {
        unsigned v = Yb[(size_t)r * 64 + w];
        accA += gelu_f(fmaf(bflo(v), sA, hA));
        accB += gelu_f(fmaf(bfhi(v), sB, hB));
    }
    part[rofs][2 * w]     = accA;
    part[rofs][2 * w + 1] = accB;
    __syncthreads();
    if (tid < 128)
        pooled[tid] = (hi > lo) ? (part[0][tid] + part[1][tid]) / (float)(hi - lo) : 0.0f;
    __syncthreads();
    if (tid < 64) {
        float hs = bl1[tid];
        #pragma unroll 4
        for (int k = 0; k < 128; ++k)
            hs = fmaf(pooled[k], Wl1[k * 64 + tid], hs);
        float e = (hs > 0.0f) ? hs : expm1f(hs);
        float pv = e * Wl2[tid];
        #pragma unroll
        for (int o = 32; o > 0; o >>= 1)
            pv += __shfl_down(pv, o);
        if (tid == 0) out[gidx] = pv + bl2[0];
    }
}

// ---------------- host launch ----------------

extern "C" void kernel_launch(void* const* d_in, const int* in_sizes, int n_in,
                              void* d_out, int out_size, void* d_ws, size_t ws_size,
                              hipStream_t stream) {
    const float* x   = (const float*)d_in[0];
    const int*   ei  = (const int*)d_in[1];
    const int*   bat = (const int*)d_in[2];
    const float* W1  = (const float*)d_in[3];
    const float* b1  = (const float*)d_in[4];
    const float* g1  = (const float*)d_in[5];
    const float* be1 = (const float*)d_in[6];
    const float* W2  = (const float*)d_in[7];
    const float* b2  = (const float*)d_in[8];
    const float* g2  = (const float*)d_in[9];
    const float* be2 = (const float*)d_in[10];
    const float* W3  = (const float*)d_in[11];
    const float* b3  = (const float*)d_in[12];
    const float* g3  = (const float*)d_in[13];
    const float* be3 = (const float*)d_in[14];
    const float* Wl1 = (const float*)d_in[15];
    const float* bl1 = (const float*)d_in[16];
    const float* Wl2 = (const float*)d_in[17];
    const float* bl2 = (const float*)d_in[18];
    float* out = (float*)d_out;

    char* ws = (char*)d_ws;
    size_t off = 0;
    auto alloc = [&](size_t bytes) -> char* {
        char* p = ws + off;
        off += (bytes + 255) & ~(size_t)255;
        return p;
    };
    int*      gcnt    = (int*)alloc(NB_BUCK * sizeof(int));
    unsigned* epack   = (unsigned*)alloc(((size_t)NB_BUCK * BUCK_CAP + 64) * sizeof(unsigned));
    int*      rowp    = (int*)alloc(N_NODES * sizeof(int));
    int*      rowpEnd = (int*)alloc(N_NODES * sizeof(int));
    float*    dinv    = (float*)alloc(N_NODES * sizeof(float));
    int*      col     = (int*)alloc(((size_t)NB_BUCK * BUCK_CAP + 64) * sizeof(int));
    unsigned* Xb      = (unsigned*)alloc((size_t)(N_NODES + 1) * 32 * sizeof(unsigned));
    unsigned* Ybuf    = (unsigned*)alloc((size_t)N_NODES * 64 * sizeof(unsigned));
    unsigned* Hbuf    = (unsigned*)alloc((size_t)(N_NODES + 1) * 64 * sizeof(unsigned));
    float*    stats   = (float*)alloc(3 * 256 * sizeof(float));
    unsigned* Wt2     = (unsigned*)alloc(8192 * sizeof(unsigned));
    unsigned* Wt3     = (unsigned*)alloc(8192 * sizeof(unsigned));

    // ---- graph structure + casts ----
    k_zero2<<<1, 1024, 0, stream>>>(gcnt, stats, Xb + (size_t)N_NODES * 32,
                                    Hbuf + (size_t)N_NODES * 64);
    k_wcast<<<64, 256, 0, stream>>>(W2, W3, Wt2, Wt3);
    k_bin<<<BIN_GRID, 256, 0, stream>>>(ei, gcnt, epack);
    k_fill<<<NB_BUCK, BUCK_SIZE, 0, stream>>>(gcnt, epack, rowp, rowpEnd, dinv, col);
    k_castx<<<(N_NODES * 32 + 255) / 256, 256, 0, stream>>>(x, dinv, Xb);

    const int gemm_blocks = (N_NODES + 63) / 64;
    const int conv_blocks = (N_NODES + 3) / 4;

    // ---- layer 1 (fused aggregate + GEMM) ----
    k_conv1<<<(N_NODES + C1_NODES - 1) / C1_NODES, 512, 0, stream>>>(
        Xb, rowp, rowpEnd, col, dinv, W1, b1, Ybuf);
    k_statsb<<<1024, 256, 0, stream>>>(Ybuf, stats + 0 * 256);

    // ---- layer 2 ----
    k_gemm128m<<<gemm_blocks, 256, 0, stream>>>(Ybuf, stats + 0 * 256, g1, be1, Wt2, dinv, Hbuf);
    k_convb<<<conv_blocks, 256, 0, stream>>>(Hbuf, rowp, rowpEnd, col, dinv, b2, Ybuf);
    k_statsb<<<1024, 256, 0, stream>>>(Ybuf, stats + 1 * 256);

    // ---- layer 3 ----
    k_gemm128m<<<gemm_blocks, 256, 0, stream>>>(Ybuf, stats + 1 * 256, g2, be2, Wt3, dinv, Hbuf);
    k_convb<<<conv_blocks, 256, 0, stream>>>(Hbuf, rowp, rowpEnd, col, dinv, b3, Ybuf);
    k_statsb<<<1024, 256, 0, stream>>>(Ybuf, stats + 2 * 256);

    // ---- pool + head ----
    k_pool_mlp<<<NUM_GRAPHS, 128, 0, stream>>>(Ybuf, stats + 2 * 256, g3, be3, bat,
                                               Wl1, bl1, Wl2, bl2, out);
}